// Round 1
// baseline (9616.859 us; speedup 1.0000x reference)
//
#include <hip/hip_runtime.h>
#include <math.h>

#define BB 4
#define TT 2048
#define DIMM 512
#define HEADS 8
#define HDIM 64
#define RANKK 256
#define WINN 256

static constexpr int BT = BB * TT; // 8192

// ---------------- trig table (double precision, one-time) ----------------
__global__ void trig_kernel(float* __restrict__ cosT, float* __restrict__ sinT) {
    int idx = blockIdx.x * blockDim.x + threadIdx.x; // < T*32
    if (idx >= TT * 32) return;
    int t = idx >> 5, f = idx & 31;
    double freq = pow(10000.0, -(double)f / 32.0);
    double ang = (double)t * freq;
    cosT[idx] = (float)cos(ang);
    sinT[idx] = (float)sin(ang);
}

// ---------------- generic f32 GEMM: C[M,N] = A[M,K] @ W[N,K]^T ----------------
// BM=BN=64, BK=16, 256 threads, 4x4 per thread.
__global__ __launch_bounds__(256) void gemm_f32(const float* __restrict__ A,
                                                const float* __restrict__ W,
                                                float* __restrict__ C,
                                                int M, int N, int K) {
    __shared__ float As[16][68];
    __shared__ float Bs[16][68];
    const int tid = threadIdx.x;
    const int m0 = blockIdx.x * 64;
    const int n0 = blockIdx.y * 64;
    const int tx = tid & 15, ty = tid >> 4;
    const int lrow = tid >> 2, lk4 = tid & 3;

    float acc[4][4] = {};

    for (int kt = 0; kt < K; kt += 16) {
        float4 av = *reinterpret_cast<const float4*>(&A[(size_t)(m0 + lrow) * K + kt + lk4 * 4]);
        float4 wv = *reinterpret_cast<const float4*>(&W[(size_t)(n0 + lrow) * K + kt + lk4 * 4]);
        __syncthreads();
        As[lk4 * 4 + 0][lrow] = av.x;
        As[lk4 * 4 + 1][lrow] = av.y;
        As[lk4 * 4 + 2][lrow] = av.z;
        As[lk4 * 4 + 3][lrow] = av.w;
        Bs[lk4 * 4 + 0][lrow] = wv.x;
        Bs[lk4 * 4 + 1][lrow] = wv.y;
        Bs[lk4 * 4 + 2][lrow] = wv.z;
        Bs[lk4 * 4 + 3][lrow] = wv.w;
        __syncthreads();
#pragma unroll
        for (int k = 0; k < 16; ++k) {
            float4 a = *reinterpret_cast<const float4*>(&As[k][ty * 4]);
            float4 b = *reinterpret_cast<const float4*>(&Bs[k][tx * 4]);
            float ar[4] = {a.x, a.y, a.z, a.w};
            float br[4] = {b.x, b.y, b.z, b.w};
#pragma unroll
            for (int i = 0; i < 4; ++i)
#pragma unroll
                for (int j = 0; j < 4; ++j)
                    acc[i][j] += ar[i] * br[j];
        }
    }
#pragma unroll
    for (int i = 0; i < 4; ++i) {
        float4 r = make_float4(acc[i][0], acc[i][1], acc[i][2], acc[i][3]);
        *reinterpret_cast<float4*>(&C[(size_t)(m0 + ty * 4 + i) * N + n0 + tx * 4]) = r;
    }
}

// ---------------- RoPE apply: src row-major [B*T, ld], head-cols h*64.. ------
// writes dst in [B*H, T, HD] layout. One thread per (b,t,h,f) pair, f in [0,32).
__global__ void rope_kernel(const float* __restrict__ src, int ld,
                            const float* __restrict__ cosT, const float* __restrict__ sinT,
                            float* __restrict__ dst) {
    int idx = blockIdx.x * 256 + threadIdx.x; // < B*T*H*32 = 2097152
    int f = idx & 31;
    int h = (idx >> 5) & 7;
    int t = (idx >> 8) & 2047;
    int b = idx >> 19;
    const float* sp = src + (size_t)(b * TT + t) * ld + h * HDIM;
    float x1 = sp[f];
    float x2 = sp[f + 32];
    float c = cosT[t * 32 + f];
    float s = sinT[t * 32 + f];
    float* dp = dst + (size_t)((b * HEADS + h) * TT + t) * HDIM;
    dp[f]      = x1 * c - x2 * s;
    dp[f + 32] = x2 * c + x1 * s;
}

// ---------------- V extract: kvlin [B*T,1024] cols 512.. -> [B*H,T,HD] --------
__global__ void copy_v_kernel(const float* __restrict__ kvlin, float* __restrict__ vws) {
    int idx = blockIdx.x * 256 + threadIdx.x; // < B*T*H*16 = 1048576
    int u = idx & 15;
    int h = (idx >> 4) & 7;
    int t = (idx >> 7) & 2047;
    int b = idx >> 18;
    float4 vv = *reinterpret_cast<const float4*>(kvlin + (size_t)(b * TT + t) * 1024 + DIMM + h * HDIM + u * 4);
    *reinterpret_cast<float4*>(vws + (size_t)((b * HEADS + h) * TT + t) * HDIM + u * 4) = vv;
}

// ---------------- RMSNorm over RANK=256, one wave per row --------------------
__global__ __launch_bounds__(64) void rmsnorm_kernel(float* __restrict__ ckv,
                                                     const float* __restrict__ w) {
    int row = blockIdx.x;
    int lane = threadIdx.x;
    float4 v = *reinterpret_cast<const float4*>(ckv + (size_t)row * RANKK + lane * 4);
    float ss = v.x * v.x + v.y * v.y + v.z * v.z + v.w * v.w;
#pragma unroll
    for (int off = 32; off > 0; off >>= 1) ss += __shfl_xor(ss, off);
    float rinv = rsqrtf(ss * (1.0f / RANKK) + 1e-6f);
    float4 wv = *reinterpret_cast<const float4*>(w + lane * 4);
    float4 o = make_float4(v.x * rinv * wv.x, v.y * rinv * wv.y,
                           v.z * rinv * wv.z, v.w * rinv * wv.w);
    *reinterpret_cast<float4*>(ckv + (size_t)row * RANKK + lane * 4) = o;
}

// ---------------- sliding-window attention -----------------------------------
// grid (T/64, B*H), 64 threads. lane = one query row. online softmax, 32-key tiles.
__global__ __launch_bounds__(64) void attn_kernel(const float* __restrict__ qws,
                                                  const float* __restrict__ kws,
                                                  const float* __restrict__ vws,
                                                  float* __restrict__ ao) {
    __shared__ float Kl[32][68];
    __shared__ float Vl[32][68];
    const int lane = threadIdx.x;
    const int t0 = blockIdx.x * 64;
    const int bh = blockIdx.y; // b*8+h
    const int t = t0 + lane;

    const float* qp = qws + ((size_t)bh * TT + t) * HDIM;
    float4 qr[16];
#pragma unroll
    for (int u = 0; u < 16; ++u) qr[u] = *reinterpret_cast<const float4*>(qp + u * 4);

    float4 oc[16];
#pragma unroll
    for (int u = 0; u < 16; ++u) oc[u] = make_float4(0.f, 0.f, 0.f, 0.f);
    float m = -INFINITY, l = 0.f;

    const int smin = max(0, t0 - WINN);
    const int smax = min(TT, t0 + 64 + WINN);
    const int r = lane >> 1, half = lane & 1;

    for (int s0 = smin; s0 < smax; s0 += 32) {
        __syncthreads();
        const float* kp = kws + ((size_t)bh * TT + s0 + r) * HDIM + half * 32;
        const float* vp = vws + ((size_t)bh * TT + s0 + r) * HDIM + half * 32;
#pragma unroll
        for (int u = 0; u < 8; ++u) {
            *reinterpret_cast<float4*>(&Kl[r][half * 32 + u * 4]) = *reinterpret_cast<const float4*>(kp + u * 4);
            *reinterpret_cast<float4*>(&Vl[r][half * 32 + u * 4]) = *reinterpret_cast<const float4*>(vp + u * 4);
        }
        __syncthreads();

        float sc[32];
        float tmax = -INFINITY;
#pragma unroll
        for (int j = 0; j < 32; ++j) {
            float s = 0.f;
#pragma unroll
            for (int u = 0; u < 16; ++u) {
                float4 kv = *reinterpret_cast<const float4*>(&Kl[j][u * 4]);
                s += qr[u].x * kv.x + qr[u].y * kv.y + qr[u].z * kv.z + qr[u].w * kv.w;
            }
            s *= 0.125f;
            int d = (s0 + j) - t;
            bool valid = (d <= WINN) && (d >= -WINN);
            sc[j] = valid ? s : -INFINITY;
            tmax = fmaxf(tmax, sc[j]);
        }

        float m_new = fmaxf(m, tmax);
        float corr = (m_new == -INFINITY) ? 1.0f : __expf(m - m_new);
        l *= corr;
#pragma unroll
        for (int u = 0; u < 16; ++u) {
            oc[u].x *= corr; oc[u].y *= corr; oc[u].z *= corr; oc[u].w *= corr;
        }
#pragma unroll
        for (int j = 0; j < 32; ++j) {
            float p = (sc[j] == -INFINITY) ? 0.f : __expf(sc[j] - m_new);
            l += p;
#pragma unroll
            for (int u = 0; u < 16; ++u) {
                float4 vv = *reinterpret_cast<const float4*>(&Vl[j][u * 4]);
                oc[u].x += p * vv.x; oc[u].y += p * vv.y;
                oc[u].z += p * vv.z; oc[u].w += p * vv.w;
            }
        }
        m = m_new;
    }

    float inv = 1.0f / l;
    int b = bh >> 3, h = bh & 7;
    float* op = ao + (size_t)(b * TT + t) * DIMM + h * HDIM;
#pragma unroll
    for (int u = 0; u < 16; ++u) {
        float4 o4 = make_float4(oc[u].x * inv, oc[u].y * inv, oc[u].z * inv, oc[u].w * inv);
        *reinterpret_cast<float4*>(op + u * 4) = o4;
    }
}

// ---------------- launch ------------------------------------------------------
extern "C" void kernel_launch(void* const* d_in, const int* in_sizes, int n_in,
                              void* d_out, int out_size, void* d_ws, size_t ws_size,
                              hipStream_t stream) {
    const float* x     = (const float*)d_in[0];
    const float* Wq    = (const float*)d_in[1];
    const float* Wkd   = (const float*)d_in[2];
    const float* wnorm = (const float*)d_in[3];
    const float* Wku   = (const float*)d_in[4];
    const float* Wout  = (const float*)d_in[5];
    float* out = (float*)d_out;
    float* ws  = (float*)d_ws;

    float* qws  = ws;              // 4,194,304 floats [B*H, T, HD]
    float* kws  = ws + 4194304;    // 4,194,304
    float* vws  = ws + 8388608;    // 4,194,304
    float* ao   = ws + 12582912;   // 4,194,304 [B*T, DIM]
    float* ckv  = ws + 16777216;   // 2,097,152 [B*T, RANK]
    float* lin  = ws + 18874368;   // 8,388,608 scratch (qlin then kvlin)
    float* cosT = ws + 27262976;   // 65,536 [T,32]
    float* sinT = cosT + 65536;    // 65,536

    trig_kernel<<<256, 256, 0, stream>>>(cosT, sinT);

    // q = x @ Wq^T  -> lin [B*T, 512]
    gemm_f32<<<dim3(BT / 64, DIMM / 64), 256, 0, stream>>>(x, Wq, lin, BT, DIMM, DIMM);
    rope_kernel<<<(BB * TT * HEADS * 32) / 256, 256, 0, stream>>>(lin, DIMM, cosT, sinT, qws);

    // c_kv = x @ Wkv_down^T -> ckv [B*T, 256], then RMSNorm in place
    gemm_f32<<<dim3(BT / 64, RANKK / 64), 256, 0, stream>>>(x, Wkd, ckv, BT, RANKK, DIMM);
    rmsnorm_kernel<<<BT, 64, 0, stream>>>(ckv, wnorm);

    // kv = ckv @ Wkv_up^T -> lin [B*T, 1024]
    gemm_f32<<<dim3(BT / 64, (2 * DIMM) / 64), 256, 0, stream>>>(ckv, Wku, lin, BT, 2 * DIMM, RANKK);
    rope_kernel<<<(BB * TT * HEADS * 32) / 256, 256, 0, stream>>>(lin, 2 * DIMM, cosT, sinT, kws);
    copy_v_kernel<<<(BB * TT * HEADS * 16) / 256, 256, 0, stream>>>(lin, vws);

    // attention
    attn_kernel<<<dim3(TT / 64, BB * HEADS), 64, 0, stream>>>(qws, kws, vws, ao);

    // out = ao @ Wout^T
    gemm_f32<<<dim3(BT / 64, DIMM / 64), 256, 0, stream>>>(ao, Wout, out, BT, DIMM, DIMM);
}

// Round 2
// 599.037 us; speedup vs baseline: 16.0539x; 16.0539x over previous
//
#include <hip/hip_runtime.h>
#include <math.h>

#define BB 4
#define TT 2048
#define DIMM 512
#define HEADS 8
#define HDIM 64
#define RANKK 256
#define WINN 256

static constexpr int BT = BB * TT; // 8192

// ---------------- trig table (double precision, one-time) ----------------
__global__ void trig_kernel(float* __restrict__ cosT, float* __restrict__ sinT) {
    int idx = blockIdx.x * blockDim.x + threadIdx.x; // < T*32
    if (idx >= TT * 32) return;
    int t = idx >> 5, f = idx & 31;
    double freq = pow(10000.0, -(double)f / 32.0);
    double ang = (double)t * freq;
    cosT[idx] = (float)cos(ang);
    sinT[idx] = (float)sin(ang);
}

// ---------------- generic f32 GEMM: C[M,N] = A[M,K] @ W[N,K]^T ----------------
// BM=BN=64, BK=16, 256 threads, 4x4 per thread.
__global__ __launch_bounds__(256) void gemm_f32(const float* __restrict__ A,
                                                const float* __restrict__ W,
                                                float* __restrict__ C,
                                                int M, int N, int K) {
    __shared__ float As[16][68];
    __shared__ float Bs[16][68];
    const int tid = threadIdx.x;
    const int m0 = blockIdx.x * 64;
    const int n0 = blockIdx.y * 64;
    const int tx = tid & 15, ty = tid >> 4;
    const int lrow = tid >> 2, lk4 = tid & 3;

    float acc[4][4] = {};

    for (int kt = 0; kt < K; kt += 16) {
        float4 av = *reinterpret_cast<const float4*>(&A[(size_t)(m0 + lrow) * K + kt + lk4 * 4]);
        float4 wv = *reinterpret_cast<const float4*>(&W[(size_t)(n0 + lrow) * K + kt + lk4 * 4]);
        __syncthreads();
        As[lk4 * 4 + 0][lrow] = av.x;
        As[lk4 * 4 + 1][lrow] = av.y;
        As[lk4 * 4 + 2][lrow] = av.z;
        As[lk4 * 4 + 3][lrow] = av.w;
        Bs[lk4 * 4 + 0][lrow] = wv.x;
        Bs[lk4 * 4 + 1][lrow] = wv.y;
        Bs[lk4 * 4 + 2][lrow] = wv.z;
        Bs[lk4 * 4 + 3][lrow] = wv.w;
        __syncthreads();
#pragma unroll
        for (int k = 0; k < 16; ++k) {
            float4 a = *reinterpret_cast<const float4*>(&As[k][ty * 4]);
            float4 b = *reinterpret_cast<const float4*>(&Bs[k][tx * 4]);
            float ar[4] = {a.x, a.y, a.z, a.w};
            float br[4] = {b.x, b.y, b.z, b.w};
#pragma unroll
            for (int i = 0; i < 4; ++i)
#pragma unroll
                for (int j = 0; j < 4; ++j)
                    acc[i][j] += ar[i] * br[j];
        }
    }
#pragma unroll
    for (int i = 0; i < 4; ++i) {
        float4 r = make_float4(acc[i][0], acc[i][1], acc[i][2], acc[i][3]);
        *reinterpret_cast<float4*>(&C[(size_t)(m0 + ty * 4 + i) * N + n0 + tx * 4]) = r;
    }
}

// ---------------- RoPE apply: src row-major [B*T, ld], head-cols h*64.. ------
__global__ void rope_kernel(const float* __restrict__ src, int ld,
                            const float* __restrict__ cosT, const float* __restrict__ sinT,
                            float* __restrict__ dst) {
    int idx = blockIdx.x * 256 + threadIdx.x; // < B*T*H*32 = 2097152
    int f = idx & 31;
    int h = (idx >> 5) & 7;
    int t = (idx >> 8) & 2047;
    int b = idx >> 19;
    const float* sp = src + (size_t)(b * TT + t) * ld + h * HDIM;
    float x1 = sp[f];
    float x2 = sp[f + 32];
    float c = cosT[t * 32 + f];
    float s = sinT[t * 32 + f];
    float* dp = dst + (size_t)((b * HEADS + h) * TT + t) * HDIM;
    dp[f]      = x1 * c - x2 * s;
    dp[f + 32] = x2 * c + x1 * s;
}

// ---------------- V extract: kvlin [B*T,1024] cols 512.. -> [B*H,T,HD] --------
__global__ void copy_v_kernel(const float* __restrict__ kvlin, float* __restrict__ vws) {
    int idx = blockIdx.x * 256 + threadIdx.x; // < B*T*H*16 = 1048576
    int u = idx & 15;
    int h = (idx >> 4) & 7;
    int t = (idx >> 7) & 2047;
    int b = idx >> 18;
    float4 vv = *reinterpret_cast<const float4*>(kvlin + (size_t)(b * TT + t) * 1024 + DIMM + h * HDIM + u * 4);
    *reinterpret_cast<float4*>(vws + (size_t)((b * HEADS + h) * TT + t) * HDIM + u * 4) = vv;
}

// ---------------- RMSNorm over RANK=256, one wave per row --------------------
__global__ __launch_bounds__(64) void rmsnorm_kernel(float* __restrict__ ckv,
                                                     const float* __restrict__ w) {
    int row = blockIdx.x;
    int lane = threadIdx.x;
    float4 v = *reinterpret_cast<const float4*>(ckv + (size_t)row * RANKK + lane * 4);
    float ss = v.x * v.x + v.y * v.y + v.z * v.z + v.w * v.w;
#pragma unroll
    for (int off = 32; off > 0; off >>= 1) ss += __shfl_xor(ss, off);
    float rinv = rsqrtf(ss * (1.0f / RANKK) + 1e-6f);
    float4 wv = *reinterpret_cast<const float4*>(w + lane * 4);
    float4 o = make_float4(v.x * rinv * wv.x, v.y * rinv * wv.y,
                           v.z * rinv * wv.z, v.w * rinv * wv.w);
    *reinterpret_cast<float4*>(ckv + (size_t)row * RANKK + lane * 4) = o;
}

// ---------------- sliding-window attention (spill-free) -----------------------
// grid (T/64, B*H), 256 threads = 4 waves. Each block: 64 queries.
// thread = (query, chunk): q_local = wave*16 + (lane>>2), chunk c = lane&3
// owns 16 floats of head dim. Score dot reduced over 4 chunk-lanes via shfl_xor.
#define NEG_BIG (-1e30f)
__global__ __launch_bounds__(256) void attn_kernel(const float* __restrict__ qws,
                                                   const float* __restrict__ kws,
                                                   const float* __restrict__ vws,
                                                   float* __restrict__ ao) {
    __shared__ float Kl[32][64];
    __shared__ float Vl[32][64];
    const int tid = threadIdx.x;
    const int lane = tid & 63;
    const int wave = tid >> 6;
    const int c = lane & 3;           // head-dim chunk
    const int qi = wave * 16 + (lane >> 2); // 0..63 local query
    const int t0 = blockIdx.x * 64;
    const int bh = blockIdx.y;        // b*8+h
    const int t = t0 + qi;            // global query index

    // load q chunk (16 floats)
    const float* qp = qws + ((size_t)bh * TT + t) * HDIM + c * 16;
    float4 qc[4];
#pragma unroll
    for (int u = 0; u < 4; ++u) qc[u] = *reinterpret_cast<const float4*>(qp + u * 4);

    float4 oc[4];
#pragma unroll
    for (int u = 0; u < 4; ++u) oc[u] = make_float4(0.f, 0.f, 0.f, 0.f);
    float m = NEG_BIG, l = 0.f;

    const int smin = max(0, t0 - WINN);
    const int smax = min(TT, t0 + 64 + WINN);

    // tile-load indexing: 256 threads cover 16 rows x 16 float4-cols
    const int ld_row = tid >> 4;      // 0..15
    const int ld_c4 = (tid & 15) * 4; // float col 0,4,..,60

    for (int s0 = smin; s0 < smax; s0 += 32) {
        __syncthreads();
        const float* kp = kws + ((size_t)bh * TT + s0 + ld_row) * HDIM + ld_c4;
        const float* vp = vws + ((size_t)bh * TT + s0 + ld_row) * HDIM + ld_c4;
        *reinterpret_cast<float4*>(&Kl[ld_row][ld_c4])      = *reinterpret_cast<const float4*>(kp);
        *reinterpret_cast<float4*>(&Kl[ld_row + 16][ld_c4]) = *reinterpret_cast<const float4*>(kp + 16 * HDIM);
        *reinterpret_cast<float4*>(&Vl[ld_row][ld_c4])      = *reinterpret_cast<const float4*>(vp);
        *reinterpret_cast<float4*>(&Vl[ld_row + 16][ld_c4]) = *reinterpret_cast<const float4*>(vp + 16 * HDIM);
        __syncthreads();

        float sc[32];
        float tmax = NEG_BIG;
#pragma unroll
        for (int j = 0; j < 32; ++j) {
            const float* kr = &Kl[j][c * 16];
            float s = 0.f;
#pragma unroll
            for (int u = 0; u < 4; ++u) {
                float4 kv = *reinterpret_cast<const float4*>(kr + u * 4);
                s += qc[u].x * kv.x + qc[u].y * kv.y + qc[u].z * kv.z + qc[u].w * kv.w;
            }
            // reduce over the 4 chunk-lanes
            s += __shfl_xor(s, 1);
            s += __shfl_xor(s, 2);
            s *= 0.125f;
            int d = (s0 + j) - t;
            bool valid = (d <= WINN) && (d >= -WINN);
            sc[j] = valid ? s : NEG_BIG;
            tmax = fmaxf(tmax, sc[j]);
        }

        float m_new = fmaxf(m, tmax);
        float corr = __expf(m - m_new); // m=NEG_BIG & finite m_new -> 0; both NEG_BIG -> exp(0)=1, l=0 anyway
        l *= corr;
#pragma unroll
        for (int u = 0; u < 4; ++u) {
            oc[u].x *= corr; oc[u].y *= corr; oc[u].z *= corr; oc[u].w *= corr;
        }
#pragma unroll
        for (int j = 0; j < 32; ++j) {
            float p = __expf(sc[j] - m_new); // masked: exp(NEG_BIG - finite) = 0
            l += p;
            const float* vr = &Vl[j][c * 16];
#pragma unroll
            for (int u = 0; u < 4; ++u) {
                float4 vv = *reinterpret_cast<const float4*>(vr + u * 4);
                oc[u].x += p * vv.x; oc[u].y += p * vv.y;
                oc[u].z += p * vv.z; oc[u].w += p * vv.w;
            }
        }
        m = m_new;
    }

    float inv = 1.0f / l;
    int b = bh >> 3, h = bh & 7;
    float* op = ao + (size_t)(b * TT + t) * DIMM + h * HDIM + c * 16;
#pragma unroll
    for (int u = 0; u < 4; ++u) {
        float4 o4 = make_float4(oc[u].x * inv, oc[u].y * inv, oc[u].z * inv, oc[u].w * inv);
        *reinterpret_cast<float4*>(op + u * 4) = o4;
    }
}

// ---------------- launch ------------------------------------------------------
extern "C" void kernel_launch(void* const* d_in, const int* in_sizes, int n_in,
                              void* d_out, int out_size, void* d_ws, size_t ws_size,
                              hipStream_t stream) {
    const float* x     = (const float*)d_in[0];
    const float* Wq    = (const float*)d_in[1];
    const float* Wkd   = (const float*)d_in[2];
    const float* wnorm = (const float*)d_in[3];
    const float* Wku   = (const float*)d_in[4];
    const float* Wout  = (const float*)d_in[5];
    float* out = (float*)d_out;
    float* ws  = (float*)d_ws;

    float* qws  = ws;              // 4,194,304 floats [B*H, T, HD]
    float* kws  = ws + 4194304;    // 4,194,304
    float* vws  = ws + 8388608;    // 4,194,304
    float* ao   = ws + 12582912;   // 4,194,304 [B*T, DIM]
    float* ckv  = ws + 16777216;   // 2,097,152 [B*T, RANK]
    float* lin  = ws + 18874368;   // 8,388,608 scratch (qlin then kvlin)
    float* cosT = ws + 27262976;   // 65,536 [T,32]
    float* sinT = cosT + 65536;    // 65,536

    trig_kernel<<<256, 256, 0, stream>>>(cosT, sinT);

    // q = x @ Wq^T  -> lin [B*T, 512]
    gemm_f32<<<dim3(BT / 64, DIMM / 64), 256, 0, stream>>>(x, Wq, lin, BT, DIMM, DIMM);
    rope_kernel<<<(BB * TT * HEADS * 32) / 256, 256, 0, stream>>>(lin, DIMM, cosT, sinT, qws);

    // c_kv = x @ Wkv_down^T -> ckv [B*T, 256], then RMSNorm in place
    gemm_f32<<<dim3(BT / 64, RANKK / 64), 256, 0, stream>>>(x, Wkd, ckv, BT, RANKK, DIMM);
    rmsnorm_kernel<<<BT, 64, 0, stream>>>(ckv, wnorm);

    // kv = ckv @ Wkv_up^T -> lin [B*T, 1024]
    gemm_f32<<<dim3(BT / 64, (2 * DIMM) / 64), 256, 0, stream>>>(ckv, Wku, lin, BT, 2 * DIMM, RANKK);
    rope_kernel<<<(BB * TT * HEADS * 32) / 256, 256, 0, stream>>>(lin, 2 * DIMM, cosT, sinT, kws);
    copy_v_kernel<<<(BB * TT * HEADS * 16) / 256, 256, 0, stream>>>(lin, vws);

    // attention
    attn_kernel<<<dim3(TT / 64, BB * HEADS), 256, 0, stream>>>(qws, kws, vws, ao);

    // out = ao @ Wout^T
    gemm_f32<<<dim3(BT / 64, DIMM / 64), 256, 0, stream>>>(ao, Wout, out, BT, DIMM, DIMM);
}

// Round 3
// 131.558 us; speedup vs baseline: 73.1000x; 4.5534x over previous
//
#include <hip/hip_runtime.h>
#include <math.h>

#define BB 4
#define TT 2048
#define DIMM 512
#define HEADS 8
#define HDIM 64
#define RANKK 256
#define WINN 256
#define NEG_BIG (-1e30f)

static constexpr int BT = BB * TT; // 8192

typedef short bf8_t __attribute__((ext_vector_type(8)));   // 8 bf16 payload
typedef float f32x4 __attribute__((ext_vector_type(4)));

__device__ __forceinline__ unsigned short f2bf(float f) {
    unsigned u = __float_as_uint(f);
    u += 0x7fffu + ((u >> 16) & 1u);     // round-to-nearest-even
    return (unsigned short)(u >> 16);
}

// ---------------- trig table (double precision, one-time) ----------------
__global__ void trig_kernel(float* __restrict__ cosT, float* __restrict__ sinT) {
    int idx = blockIdx.x * blockDim.x + threadIdx.x;
    if (idx >= TT * 32) return;
    int t = idx >> 5, f = idx & 31;
    double freq = pow(10000.0, -(double)f / 32.0);
    double ang = (double)t * freq;
    cosT[idx] = (float)cos(ang);
    sinT[idx] = (float)sin(ang);
}

// ---------------- f32 -> bf16 conversion (n multiple of 1024) ----------------
__global__ void conv_bf(const float* __restrict__ src, unsigned short* __restrict__ dst) {
    int i = (blockIdx.x * 256 + threadIdx.x) * 4;
    float4 v = *reinterpret_cast<const float4*>(src + i);
    ushort4 o = make_ushort4(f2bf(v.x), f2bf(v.y), f2bf(v.z), f2bf(v.w));
    *reinterpret_cast<ushort4*>(dst + i) = o;
}

// ---------------- bf16 MFMA GEMM: C[M,N] f32 = A[M,K]bf16 @ W[N,K]bf16^T -----
// 128x128 tile, 4 waves (2x2 of 64x64), BK=32.
__global__ __launch_bounds__(256) void gemm_bf(const unsigned short* __restrict__ A,
                                               const unsigned short* __restrict__ W,
                                               float* __restrict__ C,
                                               int M, int N, int K) {
    __shared__ unsigned short As[128][56];  // pad to 56 elems = 112B stride
    __shared__ unsigned short Ws[128][56];
    const int tid = threadIdx.x;
    const int lane = tid & 63, w = tid >> 6;
    const int lr = lane & 15, hi = lane >> 4;
    const int m0 = blockIdx.x * 128, n0 = blockIdx.y * 128;
    const int wr = (w >> 1) * 64, wc = (w & 1) * 64;
    const int srow = tid >> 2, sseg = tid & 3;

    f32x4 acc[4][4];
#pragma unroll
    for (int i = 0; i < 4; ++i)
#pragma unroll
        for (int j = 0; j < 4; ++j) acc[i][j] = 0.0f;

    for (int kt = 0; kt < K; kt += 32) {
        __syncthreads();
        *reinterpret_cast<int4*>(&As[srow][sseg * 8]) =
            *reinterpret_cast<const int4*>(A + (size_t)(m0 + srow) * K + kt + sseg * 8);
        *reinterpret_cast<int4*>(&As[srow + 64][sseg * 8]) =
            *reinterpret_cast<const int4*>(A + (size_t)(m0 + srow + 64) * K + kt + sseg * 8);
        *reinterpret_cast<int4*>(&Ws[srow][sseg * 8]) =
            *reinterpret_cast<const int4*>(W + (size_t)(n0 + srow) * K + kt + sseg * 8);
        *reinterpret_cast<int4*>(&Ws[srow + 64][sseg * 8]) =
            *reinterpret_cast<const int4*>(W + (size_t)(n0 + srow + 64) * K + kt + sseg * 8);
        __syncthreads();

        bf8_t af[4], bfr[4];
#pragma unroll
        for (int i = 0; i < 4; ++i)
            af[i] = *reinterpret_cast<const bf8_t*>(&As[wr + i * 16 + lr][hi * 8]);
#pragma unroll
        for (int j = 0; j < 4; ++j)
            bfr[j] = *reinterpret_cast<const bf8_t*>(&Ws[wc + j * 16 + lr][hi * 8]);
#pragma unroll
        for (int i = 0; i < 4; ++i)
#pragma unroll
            for (int j = 0; j < 4; ++j)
                acc[i][j] = __builtin_amdgcn_mfma_f32_16x16x32_bf16(af[i], bfr[j], acc[i][j], 0, 0, 0);
    }

#pragma unroll
    for (int i = 0; i < 4; ++i)
#pragma unroll
        for (int j = 0; j < 4; ++j)
#pragma unroll
            for (int r = 0; r < 4; ++r)
                C[(size_t)(m0 + wr + i * 16 + 4 * hi + r) * N + n0 + wc + j * 16 + lr] = acc[i][j][r];
}

// ---------------- RoPE: src f32 [B*T, ld] cols off+h*64.. -> dst bf16 [B*H,T,HD]
__global__ void rope_bf(const float* __restrict__ src, int ld, int off,
                        const float* __restrict__ cosT, const float* __restrict__ sinT,
                        unsigned short* __restrict__ dst) {
    int idx = blockIdx.x * 256 + threadIdx.x; // < B*T*H*32
    int f = idx & 31;
    int h = (idx >> 5) & 7;
    int t = (idx >> 8) & 2047;
    int b = idx >> 19;
    const float* sp = src + (size_t)(b * TT + t) * ld + off + h * HDIM;
    float x1 = sp[f];
    float x2 = sp[f + 32];
    float c = cosT[t * 32 + f];
    float s = sinT[t * 32 + f];
    unsigned short* dp = dst + (size_t)((b * HEADS + h) * TT + t) * HDIM;
    dp[f]      = f2bf(x1 * c - x2 * s);
    dp[f + 32] = f2bf(x2 * c + x1 * s);
}

// ---------------- RMSNorm: lin1 f32 [B*T,768] cols 512.. -> ckvb bf16 [B*T,256]
__global__ __launch_bounds__(64) void rmsnorm_bf(const float* __restrict__ lin1,
                                                 const float* __restrict__ wn,
                                                 unsigned short* __restrict__ ckvb) {
    int row = blockIdx.x;
    int lane = threadIdx.x;
    const float* p = lin1 + (size_t)row * 768 + 512;
    float4 v = *reinterpret_cast<const float4*>(p + lane * 4);
    float ss = v.x * v.x + v.y * v.y + v.z * v.z + v.w * v.w;
#pragma unroll
    for (int off = 32; off > 0; off >>= 1) ss += __shfl_xor(ss, off);
    float rinv = rsqrtf(ss * (1.0f / RANKK) + 1e-6f);
    float4 wv = *reinterpret_cast<const float4*>(wn + lane * 4);
    ushort4 o = make_ushort4(f2bf(v.x * rinv * wv.x), f2bf(v.y * rinv * wv.y),
                             f2bf(v.z * rinv * wv.z), f2bf(v.w * rinv * wv.w));
    *reinterpret_cast<ushort4*>(ckvb + (size_t)row * RANKK + lane * 4) = o;
}

// ---------------- V transpose: kvlin f32 [B*T,1024] cols 512.. -> vT bf16 [B*H,HD,T]
__global__ __launch_bounds__(256) void transpose_v(const float* __restrict__ kvlin,
                                                   unsigned short* __restrict__ vT) {
    __shared__ unsigned short TL[64][72];
    int tid = threadIdx.x;
    int t0 = blockIdx.x * 64, bh = blockIdx.y;
    int b = bh >> 3, h = bh & 7;
    int row = tid >> 4, c = tid & 15;
#pragma unroll
    for (int p = 0; p < 4; ++p) {
        int key = row + p * 16;
        float4 v = *reinterpret_cast<const float4*>(
            kvlin + ((size_t)(b * TT) + t0 + key) * 1024 + DIMM + h * HDIM + c * 4);
        TL[c * 4 + 0][key] = f2bf(v.x);
        TL[c * 4 + 1][key] = f2bf(v.y);
        TL[c * 4 + 2][key] = f2bf(v.z);
        TL[c * 4 + 3][key] = f2bf(v.w);
    }
    __syncthreads();
    int hd = tid >> 3, seg = tid & 7;
#pragma unroll
    for (int p = 0; p < 2; ++p) {
        int hh = hd + p * 32;
        *reinterpret_cast<int4*>(vT + ((size_t)bh * 64 + hh) * TT + t0 + seg * 8) =
            *reinterpret_cast<int4*>(&TL[hh][seg * 8]);
    }
}

// ---------------- MFMA flash attention -----------------------------------
// grid (T/64, B*H), 256 thr = 4 waves. Wave w: 16 queries. 64-key tiles.
__global__ __launch_bounds__(256) void attn_mfma(const unsigned short* __restrict__ qbf,
                                                 const unsigned short* __restrict__ kbf,
                                                 const unsigned short* __restrict__ vT,
                                                 unsigned short* __restrict__ aob) {
    __shared__ unsigned short Kl[64][72];
    __shared__ unsigned short Vt[64][72];
    __shared__ unsigned short Pl[64][72];
    const int tid = threadIdx.x;
    const int lane = tid & 63, w = tid >> 6;
    const int lr = lane & 15, hi = lane >> 4;
    const int t0 = blockIdx.x * 64, bh = blockIdx.y;

    // Q fragments, register-resident for whole kernel
    const unsigned short* qp = qbf + ((size_t)bh * TT + t0 + w * 16 + lr) * HDIM;
    bf8_t qa[2];
    qa[0] = *reinterpret_cast<const bf8_t*>(qp + hi * 8);
    qa[1] = *reinterpret_cast<const bf8_t*>(qp + 32 + hi * 8);

    f32x4 oc[4];
#pragma unroll
    for (int f = 0; f < 4; ++f) oc[f] = 0.0f;
    float m[4], l[4];
#pragma unroll
    for (int r = 0; r < 4; ++r) { m[r] = NEG_BIG; l[r] = 0.f; }

    const int smin = max(0, t0 - WINN);
    const int smax = min(TT, t0 + 64 + WINN);
    const int srow = tid >> 2, sseg = tid & 3;

    for (int s0 = smin; s0 < smax; s0 += 64) {
        __syncthreads();
        {   // stage K tile [64 keys][64 hd] and Vt tile [64 hd][64 keys]
            const unsigned short* kg = kbf + ((size_t)bh * TT + s0 + srow) * HDIM;
            *reinterpret_cast<int4*>(&Kl[srow][sseg * 8]) =
                *reinterpret_cast<const int4*>(kg + sseg * 8);
            *reinterpret_cast<int4*>(&Kl[srow][32 + sseg * 8]) =
                *reinterpret_cast<const int4*>(kg + 32 + sseg * 8);
            const unsigned short* vg = vT + ((size_t)bh * 64 + srow) * TT + s0;
            *reinterpret_cast<int4*>(&Vt[srow][sseg * 8]) =
                *reinterpret_cast<const int4*>(vg + sseg * 8);
            *reinterpret_cast<int4*>(&Vt[srow][32 + sseg * 8]) =
                *reinterpret_cast<const int4*>(vg + 32 + sseg * 8);
        }
        __syncthreads();

        // QK^T: S[16q][64key] per wave
        f32x4 sacc[4];
#pragma unroll
        for (int f = 0; f < 4; ++f) sacc[f] = 0.0f;
#pragma unroll
        for (int ks = 0; ks < 2; ++ks)
#pragma unroll
            for (int f = 0; f < 4; ++f) {
                bf8_t kb = *reinterpret_cast<const bf8_t*>(&Kl[f * 16 + lr][ks * 32 + hi * 8]);
                sacc[f] = __builtin_amdgcn_mfma_f32_16x16x32_bf16(qa[ks], kb, sacc[f], 0, 0, 0);
            }

        float sv[4][4]; // [keyfrag f][row r]
#pragma unroll
        for (int f = 0; f < 4; ++f)
#pragma unroll
            for (int r = 0; r < 4; ++r) sv[f][r] = sacc[f][r] * 0.125f;

        bool edge = (s0 - t0 < -192) || (s0 - t0 > 192);
        if (edge) {
#pragma unroll
            for (int f = 0; f < 4; ++f)
#pragma unroll
                for (int r = 0; r < 4; ++r) {
                    int d = (s0 + f * 16 + lr) - (t0 + w * 16 + 4 * hi + r);
                    if (d > WINN || d < -WINN) sv[f][r] = NEG_BIG;
                }
        }

        // row max over 64 keys: partial over f, then 16-lane butterfly
        float tmax[4];
#pragma unroll
        for (int r = 0; r < 4; ++r)
            tmax[r] = fmaxf(fmaxf(sv[0][r], sv[1][r]), fmaxf(sv[2][r], sv[3][r]));
#pragma unroll
        for (int r = 0; r < 4; ++r) {
            tmax[r] = fmaxf(tmax[r], __shfl_xor(tmax[r], 1));
            tmax[r] = fmaxf(tmax[r], __shfl_xor(tmax[r], 2));
            tmax[r] = fmaxf(tmax[r], __shfl_xor(tmax[r], 4));
            tmax[r] = fmaxf(tmax[r], __shfl_xor(tmax[r], 8));
        }
#pragma unroll
        for (int r = 0; r < 4; ++r) {
            float mn = fmaxf(m[r], tmax[r]);
            float corr = __expf(m[r] - mn);
            m[r] = mn;
            l[r] *= corr;
#pragma unroll
            for (int f = 0; f < 4; ++f) oc[f][r] *= corr;
        }
        float ps[4] = {0.f, 0.f, 0.f, 0.f};
#pragma unroll
        for (int f = 0; f < 4; ++f)
#pragma unroll
            for (int r = 0; r < 4; ++r) {
                float p = __expf(sv[f][r] - m[r]);
                sv[f][r] = p;
                ps[r] += p;
            }
#pragma unroll
        for (int r = 0; r < 4; ++r) {
            ps[r] += __shfl_xor(ps[r], 1);
            ps[r] += __shfl_xor(ps[r], 2);
            ps[r] += __shfl_xor(ps[r], 4);
            ps[r] += __shfl_xor(ps[r], 8);
            l[r] += ps[r];
        }

        // P -> LDS (wave-private rows, no cross-wave barrier needed)
#pragma unroll
        for (int f = 0; f < 4; ++f)
#pragma unroll
            for (int r = 0; r < 4; ++r)
                Pl[w * 16 + 4 * hi + r][f * 16 + lr] = f2bf(sv[f][r]);

        // PV: out[16q][64hd] += P[16q][64key] * V[64key][64hd]
#pragma unroll
        for (int ks = 0; ks < 2; ++ks) {
            bf8_t pa = *reinterpret_cast<const bf8_t*>(&Pl[w * 16 + lr][ks * 32 + hi * 8]);
#pragma unroll
            for (int f = 0; f < 4; ++f) {
                bf8_t vb = *reinterpret_cast<const bf8_t*>(&Vt[f * 16 + lr][ks * 32 + hi * 8]);
                oc[f] = __builtin_amdgcn_mfma_f32_16x16x32_bf16(pa, vb, oc[f], 0, 0, 0);
            }
        }
    }

    // epilogue: normalize, write bf16 ao [b][t][512]
    int b = bh >> 3, h = bh & 7;
#pragma unroll
    for (int r = 0; r < 4; ++r) {
        float inv = 1.0f / l[r];
        int t = t0 + w * 16 + 4 * hi + r;
        unsigned short* op = aob + ((size_t)b * TT + t) * DIMM + h * HDIM;
#pragma unroll
        for (int f = 0; f < 4; ++f)
            op[f * 16 + lr] = f2bf(oc[f][r] * inv);
    }
}

// ---------------- launch ------------------------------------------------------
extern "C" void kernel_launch(void* const* d_in, const int* in_sizes, int n_in,
                              void* d_out, int out_size, void* d_ws, size_t ws_size,
                              hipStream_t stream) {
    const float* x     = (const float*)d_in[0];
    const float* Wq    = (const float*)d_in[1];
    const float* Wkd   = (const float*)d_in[2];
    const float* wnorm = (const float*)d_in[3];
    const float* Wku   = (const float*)d_in[4];
    const float* Wout  = (const float*)d_in[5];
    float* out = (float*)d_out;
    char* ws = (char*)d_ws;

    float*          lin1  = (float*)(ws + 0);            // [8192,768] f32   25,165,824 B
    float*          kvlin = (float*)(ws + 25165824);     // [8192,1024] f32  33,554,432 B
    unsigned short* xb    = (unsigned short*)(ws + 58720256);   // 8,388,608 B
    unsigned short* qb    = (unsigned short*)(ws + 67108864);   // 8,388,608 B
    unsigned short* kb    = (unsigned short*)(ws + 75497472);   // 8,388,608 B
    unsigned short* vT    = (unsigned short*)(ws + 83886080);   // 8,388,608 B
    unsigned short* ckvb  = (unsigned short*)(ws + 92274688);   // 4,194,304 B
    unsigned short* aob   = (unsigned short*)(ws + 96468992);   // 8,388,608 B
    unsigned short* wcomb = (unsigned short*)(ws + 104857600);  // [768,512] bf16
    unsigned short* wkub  = (unsigned short*)(ws + 105644032);  // [1024,256] bf16
    unsigned short* woutb = (unsigned short*)(ws + 106168320);  // [512,512] bf16
    float*          cosT  = (float*)(ws + 106692608);    // [2048,32] f32
    float*          sinT  = (float*)(ws + 106954752);

    trig_kernel<<<256, 256, 0, stream>>>(cosT, sinT);

    // conversions to bf16
    conv_bf<<<BT * DIMM / 1024, 256, 0, stream>>>(x, xb);
    conv_bf<<<DIMM * DIMM / 1024, 256, 0, stream>>>(Wq, wcomb);
    conv_bf<<<RANKK * DIMM / 1024, 256, 0, stream>>>(Wkd, wcomb + DIMM * DIMM);
    conv_bf<<<2 * DIMM * RANKK / 1024, 256, 0, stream>>>(Wku, wkub);
    conv_bf<<<DIMM * DIMM / 1024, 256, 0, stream>>>(Wout, woutb);

    // fused q + kv_down projection: lin1 = xb @ [Wq;Wkd]^T  [8192, 768]
    gemm_bf<<<dim3(BT / 128, 768 / 128), 256, 0, stream>>>(xb, wcomb, lin1, BT, 768, DIMM);
    rope_bf<<<(BB * TT * HEADS * 32) / 256, 256, 0, stream>>>(lin1, 768, 0, cosT, sinT, qb);
    rmsnorm_bf<<<BT, 64, 0, stream>>>(lin1, wnorm, ckvb);

    // kv up-projection: kvlin = ckvb @ Wku^T  [8192, 1024]
    gemm_bf<<<dim3(BT / 128, 1024 / 128), 256, 0, stream>>>(ckvb, wkub, kvlin, BT, 1024, RANKK);
    rope_bf<<<(BB * TT * HEADS * 32) / 256, 256, 0, stream>>>(kvlin, 1024, 0, cosT, sinT, kb);
    transpose_v<<<dim3(TT / 64, BB * HEADS), 256, 0, stream>>>(kvlin, vT);

    // attention
    attn_mfma<<<dim3(TT / 64, BB * HEADS), 256, 0, stream>>>(qb, kb, vT, aob);

    // out = aob @ Wout^T
    gemm_bf<<<dim3(BT / 128, DIMM / 128), 256, 0, stream>>>(aob, woutb, out, BT, DIMM, DIMM);
}

// Round 4
// 100.492 us; speedup vs baseline: 95.6981x; 1.3091x over previous
//
#include <hip/hip_runtime.h>
#include <math.h>

#define BB 4
#define TT 2048
#define DIMM 512
#define HEADS 8
#define HDIM 64
#define RANKK 256
#define WINN 256

static constexpr int BT = BB * TT; // 8192

typedef short bf8_t __attribute__((ext_vector_type(8)));   // 8 bf16 payload
typedef float f32x4 __attribute__((ext_vector_type(4)));

__device__ __forceinline__ unsigned short f2bf(float f) {
    unsigned u = __float_as_uint(f);
    u += 0x7fffu + ((u >> 16) & 1u);     // round-to-nearest-even
    return (unsigned short)(u >> 16);
}
__device__ __forceinline__ float bf2f(unsigned short u) {
    return __uint_as_float(((unsigned)u) << 16);
}

typedef __attribute__((address_space(1))) void gvoid_t;
typedef __attribute__((address_space(3))) void lvoid_t;
__device__ __forceinline__ void gload16(const void* g, void* l) {
    __builtin_amdgcn_global_load_lds((gvoid_t*)g, (lvoid_t*)l, 16, 0, 0);
}

// ---------------- trig table (double precision, one-time) ----------------
__global__ void trig_kernel(float* __restrict__ cosT, float* __restrict__ sinT) {
    int idx = blockIdx.x * blockDim.x + threadIdx.x;
    if (idx >= TT * 32) return;
    int t = idx >> 5, f = idx & 31;
    double freq = pow(10000.0, -(double)f / 32.0);
    double ang = (double)t * freq;
    cosT[idx] = (float)cos(ang);
    sinT[idx] = (float)sin(ang);
}

// ---------------- f32 -> bf16 conversion (n multiple of 1024) ----------------
__global__ void conv_bf(const float* __restrict__ src, unsigned short* __restrict__ dst) {
    int i = (blockIdx.x * 256 + threadIdx.x) * 4;
    float4 v = *reinterpret_cast<const float4*>(src + i);
    ushort4 o = make_ushort4(f2bf(v.x), f2bf(v.y), f2bf(v.z), f2bf(v.w));
    *reinterpret_cast<ushort4*>(dst + i) = o;
}

// ---------------- bf16 MFMA GEMM with fused epilogues ------------------------
// 128x128 tile, 4 waves (2x2 of 64x64), BK=32, linear LDS + global_load_lds.
// MODE 0: A bf16, plain f32 C        (out = aob @ Wout^T)
// MODE 1: A f32 (convert in staging); cols<512 -> q-RoPE -> O1 (qb),
//         cols>=512 -> bf16 -> O2 (ckvb0)
// MODE 2: A bf16; cols<512 -> k-RoPE -> O1 (kb); cols>=512 -> V transpose -> O2 (vT)
template<int MODE>
__global__ __launch_bounds__(256) void gemm_bf(const void* __restrict__ Ap,
                                               const unsigned short* __restrict__ W,
                                               float* __restrict__ Cf,
                                               unsigned short* __restrict__ O1,
                                               unsigned short* __restrict__ O2,
                                               const float* __restrict__ cosT,
                                               const float* __restrict__ sinT,
                                               int K, int N) {
    __shared__ __align__(16) unsigned short As[128 * 32];
    __shared__ __align__(16) unsigned short Ws[128 * 32];
    const int tid = threadIdx.x;
    const int lane = tid & 63, w = tid >> 6;
    const int lr = lane & 15, hi = lane >> 4;
    const int m0 = blockIdx.x * 128, n0 = blockIdx.y * 128;
    const int wr = (w >> 1) * 64, wc = (w & 1) * 64;

    f32x4 acc[4][4];
#pragma unroll
    for (int i = 0; i < 4; ++i)
#pragma unroll
        for (int j = 0; j < 4; ++j) acc[i][j] = 0.0f;

    for (int kt = 0; kt < K; kt += 32) {
        __syncthreads();
        {   // W staging: 512 chunks of 16B, lane-ordered for global_load_lds
            int idx = w * 128 + lane;
            gload16(W + (size_t)(n0 + (idx >> 2)) * K + kt + (idx & 3) * 8, &Ws[idx * 8]);
            idx += 64;
            gload16(W + (size_t)(n0 + (idx >> 2)) * K + kt + (idx & 3) * 8, &Ws[idx * 8]);
        }
        if constexpr (MODE == 1) {
            const float* A32 = (const float*)Ap;
            int srow = tid >> 1, half = tid & 1;
            const float* ap = A32 + (size_t)(m0 + srow) * K + kt + half * 16;
            float4 u0 = *reinterpret_cast<const float4*>(ap);
            float4 u1 = *reinterpret_cast<const float4*>(ap + 4);
            float4 u2 = *reinterpret_cast<const float4*>(ap + 8);
            float4 u3 = *reinterpret_cast<const float4*>(ap + 12);
            unsigned short* dp = &As[srow * 32 + half * 16];
            *reinterpret_cast<ushort4*>(dp + 0)  = make_ushort4(f2bf(u0.x), f2bf(u0.y), f2bf(u0.z), f2bf(u0.w));
            *reinterpret_cast<ushort4*>(dp + 4)  = make_ushort4(f2bf(u1.x), f2bf(u1.y), f2bf(u1.z), f2bf(u1.w));
            *reinterpret_cast<ushort4*>(dp + 8)  = make_ushort4(f2bf(u2.x), f2bf(u2.y), f2bf(u2.z), f2bf(u2.w));
            *reinterpret_cast<ushort4*>(dp + 12) = make_ushort4(f2bf(u3.x), f2bf(u3.y), f2bf(u3.z), f2bf(u3.w));
        } else {
            const unsigned short* A16 = (const unsigned short*)Ap;
            int idx = w * 128 + lane;
            gload16(A16 + (size_t)(m0 + (idx >> 2)) * K + kt + (idx & 3) * 8, &As[idx * 8]);
            idx += 64;
            gload16(A16 + (size_t)(m0 + (idx >> 2)) * K + kt + (idx & 3) * 8, &As[idx * 8]);
        }
        __syncthreads();

        bf8_t af[4], bw[4];
#pragma unroll
        for (int i = 0; i < 4; ++i)
            af[i] = *reinterpret_cast<const bf8_t*>(&As[(wr + i * 16 + lr) * 32 + hi * 8]);
#pragma unroll
        for (int j = 0; j < 4; ++j)
            bw[j] = *reinterpret_cast<const bf8_t*>(&Ws[(wc + j * 16 + lr) * 32 + hi * 8]);
#pragma unroll
        for (int i = 0; i < 4; ++i)
#pragma unroll
            for (int j = 0; j < 4; ++j)
                acc[i][j] = __builtin_amdgcn_mfma_f32_16x16x32_bf16(af[i], bw[j], acc[i][j], 0, 0, 0);
    }

    if constexpr (MODE == 0) {
#pragma unroll
        for (int i = 0; i < 4; ++i)
#pragma unroll
            for (int j = 0; j < 4; ++j)
#pragma unroll
                for (int r = 0; r < 4; ++r)
                    Cf[(size_t)(m0 + wr + i * 16 + 4 * hi + r) * N + n0 + wc + j * 16 + lr] = acc[i][j][r];
    } else if (n0 < 512) {
        // RoPE epilogue -> O1 in [B*H, T, HD] bf16
        int h = (n0 + wc) >> 6;
#pragma unroll
        for (int i = 0; i < 4; ++i)
#pragma unroll
            for (int j = 0; j < 2; ++j)
#pragma unroll
                for (int r = 0; r < 4; ++r) {
                    int t = m0 + wr + i * 16 + 4 * hi + r;
                    int b = t >> 11, tt = t & 2047;
                    int ff = j * 16 + lr;
                    float x1 = acc[i][j][r], x2 = acc[i][j + 2][r];
                    float cc = cosT[tt * 32 + ff], ss = sinT[tt * 32 + ff];
                    unsigned short* dp = O1 + ((size_t)((b * 8 + h) * 2048 + tt)) * 64;
                    dp[ff]      = f2bf(x1 * cc - x2 * ss);
                    dp[ff + 32] = f2bf(x2 * cc + x1 * ss);
                }
    } else if constexpr (MODE == 1) {
        // ckv region: bf16 compact [B*T, 256]
        int cb = n0 - 512 + wc;
#pragma unroll
        for (int i = 0; i < 4; ++i)
#pragma unroll
            for (int j = 0; j < 4; ++j)
#pragma unroll
                for (int r = 0; r < 4; ++r)
                    O2[(size_t)(m0 + wr + i * 16 + 4 * hi + r) * 256 + cb + j * 16 + lr] = f2bf(acc[i][j][r]);
    } else {
        // MODE 2, V region: transposed pack -> vT [B*H, HD, T] bf16
        int cb = n0 + wc - 512;
        int h = cb >> 6;
#pragma unroll
        for (int i = 0; i < 4; ++i) {
            int tb = m0 + wr + i * 16 + 4 * hi;
            int b = tb >> 11, tt = tb & 2047;
#pragma unroll
            for (int j = 0; j < 4; ++j) {
                int hd = j * 16 + lr;
                ushort4 o = make_ushort4(f2bf(acc[i][j][0]), f2bf(acc[i][j][1]),
                                         f2bf(acc[i][j][2]), f2bf(acc[i][j][3]));
                *reinterpret_cast<ushort4*>(O2 + (((size_t)(b * 8 + h) * 64 + hd) * 2048 + tt)) = o;
            }
        }
    }
}

// ---------------- RMSNorm: ckvb0 bf16 [B*T,256] -> ckvb bf16 ------------------
__global__ __launch_bounds__(256) void rmsnorm_bf(const unsigned short* __restrict__ ckvb0,
                                                  const float* __restrict__ wn,
                                                  unsigned short* __restrict__ ckvb) {
    int row = blockIdx.x * 4 + (threadIdx.x >> 6);
    int lane = threadIdx.x & 63;
    ushort4 v4 = *reinterpret_cast<const ushort4*>(ckvb0 + (size_t)row * 256 + lane * 4);
    float x0 = bf2f(v4.x), x1 = bf2f(v4.y), x2 = bf2f(v4.z), x3 = bf2f(v4.w);
    float ssum = x0 * x0 + x1 * x1 + x2 * x2 + x3 * x3;
#pragma unroll
    for (int off = 32; off > 0; off >>= 1) ssum += __shfl_xor(ssum, off);
    float rinv = rsqrtf(ssum * (1.0f / RANKK) + 1e-6f);
    float4 wv = *reinterpret_cast<const float4*>(wn + lane * 4);
    ushort4 o = make_ushort4(f2bf(x0 * rinv * wv.x), f2bf(x1 * rinv * wv.y),
                             f2bf(x2 * rinv * wv.z), f2bf(x3 * rinv * wv.w));
    *reinterpret_cast<ushort4*>(ckvb + (size_t)row * 256 + lane * 4) = o;
}

// ---------------- MFMA flash attention (fixed-max softmax, deferred l-sum) ----
// 1024 blocks (XCD-swizzled), 256 thr = 4 waves. Block: 64 queries, 64-key tiles.
__global__ __launch_bounds__(256) void attn_mfma(const unsigned short* __restrict__ qbf,
                                                 const unsigned short* __restrict__ kbf,
                                                 const unsigned short* __restrict__ vT,
                                                 unsigned short* __restrict__ aob) {
    __shared__ __align__(16) unsigned short Kl[64 * 64];
    __shared__ __align__(16) unsigned short Vl[64 * 64];
    __shared__ unsigned short Pl[64][72];
    const int tid = threadIdx.x;
    const int lane = tid & 63, w = tid >> 6;
    const int lr = lane & 15, hi = lane >> 4;

    // bijective XCD swizzle: 1024 = 8 XCDs x 128; each XCD owns 4 bh values
    const int fid = blockIdx.x;
    const int swz = (fid & 7) * 128 + (fid >> 3);
    const int t0 = (swz & 31) * 64;
    const int bh = swz >> 5;

    const unsigned short* qp = qbf + ((size_t)bh * TT + t0 + w * 16 + lr) * HDIM;
    bf8_t qa[2];
    qa[0] = *reinterpret_cast<const bf8_t*>(qp + hi * 8);
    qa[1] = *reinterpret_cast<const bf8_t*>(qp + 32 + hi * 8);

    f32x4 oc[4];
#pragma unroll
    for (int f = 0; f < 4; ++f) oc[f] = 0.0f;
    float lp[4] = {0.f, 0.f, 0.f, 0.f};

    const int smin = max(0, t0 - WINN);
    const int smax = min(TT, t0 + 64 + WINN);
    const int srow = tid >> 2, sseg = tid & 3;

    for (int s0 = smin; s0 < smax; s0 += 64) {
        __syncthreads();
        {   // stage K [64key][64hd] and V^T [64hd][64key], XOR-swizzled 16B chunks
            const unsigned short* kg = kbf + ((size_t)bh * TT + s0 + srow) * HDIM;
            const unsigned short* vg = vT + ((size_t)bh * 64 + srow) * TT + s0;
            int sw = srow & 7;
#pragma unroll
            for (int cc = 0; cc < 2; ++cc) {
                int c = sseg + cc * 4;
                int d = srow * 64 + ((c ^ sw) << 3);
                *reinterpret_cast<int4*>(&Kl[d]) = *reinterpret_cast<const int4*>(kg + c * 8);
                *reinterpret_cast<int4*>(&Vl[d]) = *reinterpret_cast<const int4*>(vg + c * 8);
            }
        }
        __syncthreads();

        // QK^T: S[16q][64key] per wave
        f32x4 sacc[4];
#pragma unroll
        for (int f = 0; f < 4; ++f) sacc[f] = 0.0f;
#pragma unroll
        for (int ks = 0; ks < 2; ++ks)
#pragma unroll
            for (int f = 0; f < 4; ++f) {
                int row = f * 16 + lr;
                bf8_t kb = *reinterpret_cast<const bf8_t*>(
                    &Kl[row * 64 + (((ks * 4 + hi) ^ (row & 7)) << 3)]);
                sacc[f] = __builtin_amdgcn_mfma_f32_16x16x32_bf16(qa[ks], kb, sacc[f], 0, 0, 0);
            }

        const int off = s0 - t0;
        const bool edge = (off < -192) || (off > 192);
#pragma unroll
        for (int f = 0; f < 4; ++f)
#pragma unroll
            for (int r = 0; r < 4; ++r) {
                float s = sacc[f][r] * 0.125f;
                float p;
                if (edge) {
                    int d = (s0 + f * 16 + lr) - (t0 + w * 16 + 4 * hi + r);
                    p = (d <= WINN && d >= -WINN) ? __expf(s) : 0.f;
                } else {
                    p = __expf(s);
                }
                lp[r] += p;
                Pl[w * 16 + 4 * hi + r][f * 16 + lr] = f2bf(p);
            }

        // PV: out[16q][64hd] += P[16q][64key] * V^T
#pragma unroll
        for (int ks = 0; ks < 2; ++ks) {
            bf8_t pa = *reinterpret_cast<const bf8_t*>(&Pl[w * 16 + lr][ks * 32 + hi * 8]);
#pragma unroll
            for (int f = 0; f < 4; ++f) {
                int row = f * 16 + lr;
                bf8_t vb = *reinterpret_cast<const bf8_t*>(
                    &Vl[row * 64 + (((ks * 4 + hi) ^ (row & 7)) << 3)]);
                oc[f] = __builtin_amdgcn_mfma_f32_16x16x32_bf16(pa, vb, oc[f], 0, 0, 0);
            }
        }
    }

    // deferred l reduction over the 16 lr lanes
#pragma unroll
    for (int r = 0; r < 4; ++r) {
        lp[r] += __shfl_xor(lp[r], 1);
        lp[r] += __shfl_xor(lp[r], 2);
        lp[r] += __shfl_xor(lp[r], 4);
        lp[r] += __shfl_xor(lp[r], 8);
    }

    int b = bh >> 3, h = bh & 7;
#pragma unroll
    for (int r = 0; r < 4; ++r) {
        float inv = 1.0f / lp[r];
        int t = t0 + w * 16 + 4 * hi + r;
        unsigned short* op = aob + ((size_t)b * TT + t) * DIMM + h * HDIM;
#pragma unroll
        for (int f = 0; f < 4; ++f)
            op[f * 16 + lr] = f2bf(oc[f][r] * inv);
    }
}

// ---------------- launch ------------------------------------------------------
extern "C" void kernel_launch(void* const* d_in, const int* in_sizes, int n_in,
                              void* d_out, int out_size, void* d_ws, size_t ws_size,
                              hipStream_t stream) {
    const float* x     = (const float*)d_in[0];
    const float* Wq    = (const float*)d_in[1];
    const float* Wkd   = (const float*)d_in[2];
    const float* wnorm = (const float*)d_in[3];
    const float* Wku   = (const float*)d_in[4];
    const float* Wout  = (const float*)d_in[5];
    float* out = (float*)d_out;
    char* ws = (char*)d_ws;

    unsigned short* qb    = (unsigned short*)(ws + 0);          // 8,388,608
    unsigned short* kb    = (unsigned short*)(ws + 8388608);    // 8,388,608
    unsigned short* vTb   = (unsigned short*)(ws + 16777216);   // 8,388,608
    unsigned short* ckvb0 = (unsigned short*)(ws + 25165824);   // 4,194,304
    unsigned short* ckvb  = (unsigned short*)(ws + 29360128);   // 4,194,304
    unsigned short* aob   = (unsigned short*)(ws + 33554432);   // 8,388,608
    unsigned short* wcomb = (unsigned short*)(ws + 41943040);   // 786,432
    unsigned short* wkub  = (unsigned short*)(ws + 42729472);   // 524,288
    unsigned short* woutb = (unsigned short*)(ws + 43253760);   // 524,288
    float*          cosT  = (float*)(ws + 43778048);            // 262,144
    float*          sinT  = (float*)(ws + 44040192);            // 262,144

    trig_kernel<<<256, 256, 0, stream>>>(cosT, sinT);
    conv_bf<<<DIMM * DIMM / 1024, 256, 0, stream>>>(Wq, wcomb);
    conv_bf<<<RANKK * DIMM / 1024, 256, 0, stream>>>(Wkd, wcomb + DIMM * DIMM);
    conv_bf<<<2 * DIMM * RANKK / 1024, 256, 0, stream>>>(Wku, wkub);
    conv_bf<<<DIMM * DIMM / 1024, 256, 0, stream>>>(Wout, woutb);

    // fused q + kv_down projection (+ q-RoPE + ckv write): [8192, 768]
    gemm_bf<1><<<dim3(BT / 128, 6), 256, 0, stream>>>(x, wcomb, nullptr, qb, ckvb0,
                                                      cosT, sinT, DIMM, 768);
    rmsnorm_bf<<<BT / 4, 256, 0, stream>>>(ckvb0, wnorm, ckvb);

    // kv up-projection (+ k-RoPE + V transpose): [8192, 1024]
    gemm_bf<2><<<dim3(BT / 128, 8), 256, 0, stream>>>(ckvb, wkub, nullptr, kb, vTb,
                                                      cosT, sinT, RANKK, 1024);

    // attention
    attn_mfma<<<1024, 256, 0, stream>>>(qb, kb, vTb, aob);

    // out = aob @ Wout^T (f32)
    gemm_bf<0><<<dim3(BT / 128, 4), 256, 0, stream>>>(aob, woutb, out, nullptr, nullptr,
                                                      nullptr, nullptr, DIMM, DIMM);
}

// Round 5
// 95.318 us; speedup vs baseline: 100.8929x; 1.0543x over previous
//
#include <hip/hip_runtime.h>
#include <math.h>

#define BB 4
#define TT 2048
#define DIMM 512
#define HEADS 8
#define HDIM 64
#define RANKK 256
#define WINN 256

static constexpr int BT = BB * TT; // 8192
#define SC2 0.1803368801111244f   // 0.125 * log2(e)

typedef short bf8_t __attribute__((ext_vector_type(8)));   // 8 bf16 payload
typedef float f32x4 __attribute__((ext_vector_type(4)));

__device__ __forceinline__ unsigned short f2bf(float f) {
    unsigned u = __float_as_uint(f);
    u += 0x7fffu + ((u >> 16) & 1u);     // round-to-nearest-even
    return (unsigned short)(u >> 16);
}
__device__ __forceinline__ float bf2f(unsigned short u) {
    return __uint_as_float(((unsigned)u) << 16);
}

typedef __attribute__((address_space(1))) void gvoid_t;
typedef __attribute__((address_space(3))) void lvoid_t;
__device__ __forceinline__ void gload16(const void* g, void* l) {
    __builtin_amdgcn_global_load_lds((gvoid_t*)g, (lvoid_t*)l, 16, 0, 0);
}
#define WAIT_VM0_BARRIER() do { \
    asm volatile("s_waitcnt vmcnt(0)" ::: "memory"); \
    __builtin_amdgcn_s_barrier(); \
    __builtin_amdgcn_sched_barrier(0); \
} while (0)

// ---------------- trig table (double precision, one-time) ----------------
__global__ void trig_kernel(float* __restrict__ cosT, float* __restrict__ sinT) {
    int idx = blockIdx.x * blockDim.x + threadIdx.x;
    if (idx >= TT * 32) return;
    int t = idx >> 5, f = idx & 31;
    double freq = pow(10000.0, -(double)f / 32.0);
    double ang = (double)t * freq;
    cosT[idx] = (float)cos(ang);
    sinT[idx] = (float)sin(ang);
}

// ---------------- f32 -> bf16 conversion (n multiple of 1024) ----------------
__global__ void conv_bf(const float* __restrict__ src, unsigned short* __restrict__ dst) {
    int i = (blockIdx.x * 256 + threadIdx.x) * 4;
    float4 v = *reinterpret_cast<const float4*>(src + i);
    *reinterpret_cast<ushort4*>(dst + i) =
        make_ushort4(f2bf(v.x), f2bf(v.y), f2bf(v.z), f2bf(v.w));
}

// Wku * wn fold: dst[e,r] = bf16(Wku[e,r] * wn[r]), row length 256
__global__ void conv_wku(const float* __restrict__ src, const float* __restrict__ wn,
                         unsigned short* __restrict__ dst) {
    int i = (blockIdx.x * 256 + threadIdx.x) * 4;
    int r = i & 255;
    float4 v = *reinterpret_cast<const float4*>(src + i);
    float4 s = *reinterpret_cast<const float4*>(wn + r);
    *reinterpret_cast<ushort4*>(dst + i) =
        make_ushort4(f2bf(v.x * s.x), f2bf(v.y * s.y), f2bf(v.z * s.z), f2bf(v.w * s.w));
}

// ---------------- per-row rsqrt(mean sq) of ckvb0 [B*T, 256] ------------------
__global__ __launch_bounds__(256) void rinv_kernel(const unsigned short* __restrict__ ckvb0,
                                                   float* __restrict__ rinv) {
    int row = blockIdx.x * 4 + (threadIdx.x >> 6);
    int lane = threadIdx.x & 63;
    ushort4 v4 = *reinterpret_cast<const ushort4*>(ckvb0 + (size_t)row * 256 + lane * 4);
    float x0 = bf2f(v4.x), x1 = bf2f(v4.y), x2 = bf2f(v4.z), x3 = bf2f(v4.w);
    float ss = x0 * x0 + x1 * x1 + x2 * x2 + x3 * x3;
#pragma unroll
    for (int off = 32; off > 0; off >>= 1) ss += __shfl_xor(ss, off);
    if (lane == 0) rinv[row] = rsqrtf(ss * (1.0f / RANKK) + 1e-6f);
}

// ---------------- bf16 MFMA GEMM, 2-phase dbuf pipeline, fused epilogues ------
// 128x128 tile, 4 waves (2x2 of 64x64), BK=32, global_load_lds staging.
// MODE 0: plain f32 C (out = aob @ Wout^T)
// MODE 1: cols<512 -> q-RoPE -> O1 (qb); cols>=512 -> bf16 -> O2 (ckvb0)
// MODE 2: cols<512 -> k-RoPE*rinv -> O1 (kb); cols>=512 -> V^T pack*rinv -> O2 (vT)
template<int MODE>
__global__ __launch_bounds__(256) void gemm_bf(const unsigned short* __restrict__ A,
                                               const unsigned short* __restrict__ W,
                                               float* __restrict__ Cf,
                                               unsigned short* __restrict__ O1,
                                               unsigned short* __restrict__ O2,
                                               const float* __restrict__ cosT,
                                               const float* __restrict__ sinT,
                                               const float* __restrict__ rinvp,
                                               int K, int N) {
    __shared__ __align__(16) unsigned short As[2][128 * 32];
    __shared__ __align__(16) unsigned short Ws[2][128 * 32];
    const int tid = threadIdx.x;
    const int lane = tid & 63, w = tid >> 6;
    const int lr = lane & 15, hi = lane >> 4;
    const int m0 = blockIdx.x * 128, n0 = blockIdx.y * 128;
    const int wr = (w >> 1) * 64, wc = (w & 1) * 64;
    const int i1 = w * 128 + lane, i2 = i1 + 64;
    const int r1 = i1 >> 2, c1 = (i1 & 3) * 8;
    const int r2 = i2 >> 2, c2 = (i2 & 3) * 8;

    f32x4 acc[4][4];
#pragma unroll
    for (int i = 0; i < 4; ++i)
#pragma unroll
        for (int j = 0; j < 4; ++j) acc[i][j] = 0.0f;

    const int NT = K >> 5;
    auto stage = [&](int t, int b) {
        const int kt = t * 32;
        gload16(A + (size_t)(m0 + r1) * K + kt + c1, &As[b][i1 * 8]);
        gload16(A + (size_t)(m0 + r2) * K + kt + c2, &As[b][i2 * 8]);
        gload16(W + (size_t)(n0 + r1) * K + kt + c1, &Ws[b][i1 * 8]);
        gload16(W + (size_t)(n0 + r2) * K + kt + c2, &Ws[b][i2 * 8]);
    };

    stage(0, 0);
    WAIT_VM0_BARRIER();
    for (int t = 0; t < NT; ++t) {
        const int cur = t & 1;
        if (t + 1 < NT) stage(t + 1, cur ^ 1);
        bf8_t af[4], bw[4];
#pragma unroll
        for (int i = 0; i < 4; ++i)
            af[i] = *reinterpret_cast<const bf8_t*>(&As[cur][(wr + i * 16 + lr) * 32 + hi * 8]);
#pragma unroll
        for (int j = 0; j < 4; ++j)
            bw[j] = *reinterpret_cast<const bf8_t*>(&Ws[cur][(wc + j * 16 + lr) * 32 + hi * 8]);
#pragma unroll
        for (int i = 0; i < 4; ++i)
#pragma unroll
            for (int j = 0; j < 4; ++j)
                acc[i][j] = __builtin_amdgcn_mfma_f32_16x16x32_bf16(af[i], bw[j], acc[i][j], 0, 0, 0);
        if (t + 1 < NT) WAIT_VM0_BARRIER();
    }

    if constexpr (MODE == 0) {
#pragma unroll
        for (int i = 0; i < 4; ++i)
#pragma unroll
            for (int j = 0; j < 4; ++j)
#pragma unroll
                for (int r = 0; r < 4; ++r)
                    Cf[(size_t)(m0 + wr + i * 16 + 4 * hi + r) * N + n0 + wc + j * 16 + lr] = acc[i][j][r];
    } else if (n0 < 512) {
        // RoPE epilogue -> O1 in [B*H, T, HD] bf16 (MODE 2 additionally scales by rinv)
        int h = (n0 + wc) >> 6;
#pragma unroll
        for (int i = 0; i < 4; ++i) {
            int tb = m0 + wr + i * 16 + 4 * hi;
            float4 rv4 = make_float4(1.f, 1.f, 1.f, 1.f);
            if constexpr (MODE == 2) rv4 = *reinterpret_cast<const float4*>(rinvp + tb);
#pragma unroll
            for (int j = 0; j < 2; ++j)
#pragma unroll
                for (int r = 0; r < 4; ++r) {
                    int t = tb + r;
                    int b = t >> 11, tt = t & 2047;
                    int ff = j * 16 + lr;
                    float rv = (&rv4.x)[r];
                    float x1 = acc[i][j][r] * rv, x2 = acc[i][j + 2][r] * rv;
                    float cc = cosT[tt * 32 + ff], ss = sinT[tt * 32 + ff];
                    unsigned short* dp = O1 + ((size_t)((b * 8 + h) * 2048 + tt)) * 64;
                    dp[ff]      = f2bf(x1 * cc - x2 * ss);
                    dp[ff + 32] = f2bf(x2 * cc + x1 * ss);
                }
        }
    } else if constexpr (MODE == 1) {
        // ckv region: bf16 compact [B*T, 256] (unnormalized; rinv applied downstream)
        int cb = n0 - 512 + wc;
#pragma unroll
        for (int i = 0; i < 4; ++i)
#pragma unroll
            for (int j = 0; j < 4; ++j)
#pragma unroll
                for (int r = 0; r < 4; ++r)
                    O2[(size_t)(m0 + wr + i * 16 + 4 * hi + r) * 256 + cb + j * 16 + lr] = f2bf(acc[i][j][r]);
    } else {
        // MODE 2, V region: transposed pack * rinv -> vT [B*H, HD, T] bf16
        int cb = n0 + wc - 512;
        int h = cb >> 6;
#pragma unroll
        for (int i = 0; i < 4; ++i) {
            int tb = m0 + wr + i * 16 + 4 * hi;
            int b = tb >> 11, tt = tb & 2047;
            float4 rv4 = *reinterpret_cast<const float4*>(rinvp + tb);
#pragma unroll
            for (int j = 0; j < 4; ++j) {
                int hd = j * 16 + lr;
                ushort4 o = make_ushort4(f2bf(acc[i][j][0] * rv4.x), f2bf(acc[i][j][1] * rv4.y),
                                         f2bf(acc[i][j][2] * rv4.z), f2bf(acc[i][j][3] * rv4.w));
                *reinterpret_cast<ushort4*>(O2 + (((size_t)(b * 8 + h) * 64 + hd) * 2048 + tt)) = o;
            }
        }
    }
}

// ---------------- MFMA flash attention, QBLK=128, 2-phase dbuf pipeline -------
// 512 blocks (XCD-swizzled), 512 thr = 8 waves. 64-key tiles, fixed-max softmax.
__global__ __launch_bounds__(512) void attn_mfma(const unsigned short* __restrict__ qbf,
                                                 const unsigned short* __restrict__ kbf,
                                                 const unsigned short* __restrict__ vT,
                                                 unsigned short* __restrict__ aob) {
    __shared__ __align__(16) unsigned short Kl[2][64 * 64];
    __shared__ __align__(16) unsigned short Vl[2][64 * 64];
    __shared__ unsigned short Pl[128][72];
    const int tid = threadIdx.x;
    const int lane = tid & 63, w = tid >> 6;        // 8 waves
    const int lr = lane & 15, hi = lane >> 4;

    // bijective XCD swizzle: 512 = 8 XCDs x 64; each XCD owns 4 bh values
    const int fid = blockIdx.x;
    const int swz = (fid & 7) * 64 + (fid >> 3);
    const int t0 = (swz & 15) * 128;
    const int bh = swz >> 4;

    const unsigned short* qp = qbf + ((size_t)bh * TT + t0 + w * 16 + lr) * HDIM;
    bf8_t qa[2];
    qa[0] = *reinterpret_cast<const bf8_t*>(qp + hi * 8);
    qa[1] = *reinterpret_cast<const bf8_t*>(qp + 32 + hi * 8);

    f32x4 oc[4];
#pragma unroll
    for (int f = 0; f < 4; ++f) oc[f] = 0.0f;
    float lp[4] = {0.f, 0.f, 0.f, 0.f};

    const int smin = max(0, t0 - WINN);
    const int smax = min(TT, t0 + 128 + WINN);
    const int NT = (smax - smin) >> 6;

    const int st_row = tid >> 3;            // 0..63
    const int st_c = tid & 7;               // 16B chunk
    const int st_cs = (st_c ^ (st_row & 7)) << 3;   // pre-swizzled source elem offset

    auto stage = [&](int t, int b) {
        const int s0 = smin + t * 64;
        gload16(kbf + ((size_t)bh * TT + s0 + st_row) * HDIM + st_cs, &Kl[b][tid * 8]);
        gload16(vT + ((size_t)bh * 64 + st_row) * TT + s0 + st_cs, &Vl[b][tid * 8]);
    };

    stage(0, 0);
    WAIT_VM0_BARRIER();
    for (int t = 0; t < NT; ++t) {
        const int cur = t & 1;
        if (t + 1 < NT) stage(t + 1, cur ^ 1);
        const int s0 = smin + t * 64;

        // QK^T: S[16q][64key] per wave
        f32x4 sacc[4];
#pragma unroll
        for (int f = 0; f < 4; ++f) sacc[f] = 0.0f;
#pragma unroll
        for (int ks = 0; ks < 2; ++ks)
#pragma unroll
            for (int f = 0; f < 4; ++f) {
                int row = f * 16 + lr;
                bf8_t kb = *reinterpret_cast<const bf8_t*>(
                    &Kl[cur][row * 64 + (((ks * 4 + hi) ^ (row & 7)) << 3)]);
                sacc[f] = __builtin_amdgcn_mfma_f32_16x16x32_bf16(qa[ks], kb, sacc[f], 0, 0, 0);
            }

        const int off_w = s0 - t0 - w * 16;
        const bool edge = (off_w + 63 > WINN) || (off_w - 15 < -WINN);
#pragma unroll
        for (int f = 0; f < 4; ++f)
#pragma unroll
            for (int r = 0; r < 4; ++r) {
                float p;
                if (edge) {
                    int d = off_w + f * 16 + lr - 4 * hi - r;
                    p = (d <= WINN && d >= -WINN) ? exp2f(sacc[f][r] * SC2) : 0.f;
                } else {
                    p = exp2f(sacc[f][r] * SC2);
                }
                lp[r] += p;
                Pl[w * 16 + 4 * hi + r][f * 16 + lr] = f2bf(p);
            }

        // PV: out[16q][64hd] += P[16q][64key] * V^T
#pragma unroll
        for (int ks = 0; ks < 2; ++ks) {
            bf8_t pa = *reinterpret_cast<const bf8_t*>(&Pl[w * 16 + lr][ks * 32 + hi * 8]);
#pragma unroll
            for (int f = 0; f < 4; ++f) {
                int row = f * 16 + lr;
                bf8_t vb = *reinterpret_cast<const bf8_t*>(
                    &Vl[cur][row * 64 + (((ks * 4 + hi) ^ (row & 7)) << 3)]);
                oc[f] = __builtin_amdgcn_mfma_f32_16x16x32_bf16(pa, vb, oc[f], 0, 0, 0);
            }
        }
        if (t + 1 < NT) WAIT_VM0_BARRIER();
    }

    // deferred l reduction over the 16 lr lanes
#pragma unroll
    for (int r = 0; r < 4; ++r) {
        lp[r] += __shfl_xor(lp[r], 1);
        lp[r] += __shfl_xor(lp[r], 2);
        lp[r] += __shfl_xor(lp[r], 4);
        lp[r] += __shfl_xor(lp[r], 8);
    }

    int b = bh >> 3, h = bh & 7;
#pragma unroll
    for (int r = 0; r < 4; ++r) {
        float inv = 1.0f / lp[r];
        int t = t0 + w * 16 + 4 * hi + r;
        unsigned short* op = aob + ((size_t)b * TT + t) * DIMM + h * HDIM;
#pragma unroll
        for (int f = 0; f < 4; ++f)
            op[f * 16 + lr] = f2bf(oc[f][r] * inv);
    }
}

// ---------------- launch ------------------------------------------------------
extern "C" void kernel_launch(void* const* d_in, const int* in_sizes, int n_in,
                              void* d_out, int out_size, void* d_ws, size_t ws_size,
                              hipStream_t stream) {
    const float* x     = (const float*)d_in[0];
    const float* Wq    = (const float*)d_in[1];
    const float* Wkd   = (const float*)d_in[2];
    const float* wnorm = (const float*)d_in[3];
    const float* Wku   = (const float*)d_in[4];
    const float* Wout  = (const float*)d_in[5];
    float* out = (float*)d_out;
    char* ws = (char*)d_ws;

    unsigned short* xb    = (unsigned short*)(ws + 0);          //  8,388,608
    unsigned short* qb    = (unsigned short*)(ws + 8388608);    //  8,388,608
    unsigned short* kb    = (unsigned short*)(ws + 16777216);   //  8,388,608
    unsigned short* vTb   = (unsigned short*)(ws + 25165824);   //  8,388,608
    unsigned short* ckvb0 = (unsigned short*)(ws + 33554432);   //  4,194,304
    unsigned short* aob   = (unsigned short*)(ws + 37748736);   //  8,388,608
    unsigned short* wcomb = (unsigned short*)(ws + 46137344);   //    786,432
    unsigned short* wkub  = (unsigned short*)(ws + 46923776);   //    524,288
    unsigned short* woutb = (unsigned short*)(ws + 47448064);   //    524,288
    float*          rinvb = (float*)(ws + 47972352);            //     32,768
    float*          cosT  = (float*)(ws + 48005120);            //    262,144
    float*          sinT  = (float*)(ws + 48267264);            //    262,144

    trig_kernel<<<256, 256, 0, stream>>>(cosT, sinT);
    conv_bf<<<BT * DIMM / 1024, 256, 0, stream>>>(x, xb);
    conv_bf<<<DIMM * DIMM / 1024, 256, 0, stream>>>(Wq, wcomb);
    conv_bf<<<RANKK * DIMM / 1024, 256, 0, stream>>>(Wkd, wcomb + DIMM * DIMM);
    conv_wku<<<2 * DIMM * RANKK / 1024, 256, 0, stream>>>(Wku, wnorm, wkub);
    conv_bf<<<DIMM * DIMM / 1024, 256, 0, stream>>>(Wout, woutb);

    // fused q + kv_down projection (+ q-RoPE, ckv write): [8192, 768]
    gemm_bf<1><<<dim3(BT / 128, 6), 256, 0, stream>>>(xb, wcomb, nullptr, qb, ckvb0,
                                                      cosT, sinT, nullptr, DIMM, 768);
    rinv_kernel<<<BT / 4, 256, 0, stream>>>(ckvb0, rinvb);

    // kv up-projection (+ k-RoPE*rinv, V^T pack*rinv): [8192, 1024]
    gemm_bf<2><<<dim3(BT / 128, 8), 256, 0, stream>>>(ckvb0, wkub, nullptr, kb, vTb,
                                                      cosT, sinT, rinvb, RANKK, 1024);

    // attention
    attn_mfma<<<512, 512, 0, stream>>>(qb, kb, vTb, aob);

    // out = aob @ Wout^T (f32)
    gemm_bf<0><<<dim3(BT / 128, 4), 256, 0, stream>>>(aob, woutb, out, nullptr, nullptr,
                                                      nullptr, nullptr, nullptr, DIMM, DIMM);
}

// Round 6
// 77.920 us; speedup vs baseline: 123.4195x; 1.2233x over previous
//
#include <hip/hip_runtime.h>
#include <math.h>

#define BB 4
#define TT 2048
#define DIMM 512
#define HEADS 8
#define HDIM 64
#define RANKK 256
#define WINN 256

static constexpr int BT = BB * TT; // 8192
#define SC2 0.1803368801111244f   // 0.125 * log2(e)

typedef short bf8_t __attribute__((ext_vector_type(8)));   // 8 bf16 payload
typedef float f32x4 __attribute__((ext_vector_type(4)));

__device__ __forceinline__ unsigned short f2bf(float f) {
    unsigned u = __float_as_uint(f);
    u += 0x7fffu + ((u >> 16) & 1u);     // round-to-nearest-even
    return (unsigned short)(u >> 16);
}
__device__ __forceinline__ float bf2f(unsigned short u) {
    return __uint_as_float(((unsigned)u) << 16);
}

typedef __attribute__((address_space(1))) void gvoid_t;
typedef __attribute__((address_space(3))) void lvoid_t;
__device__ __forceinline__ void gload16(const void* g, void* l) {
    __builtin_amdgcn_global_load_lds((gvoid_t*)g, (lvoid_t*)l, 16, 0, 0);
}
#define WAIT_VM0_BARRIER() do { \
    asm volatile("s_waitcnt vmcnt(0)" ::: "memory"); \
    __builtin_amdgcn_s_barrier(); \
    __builtin_amdgcn_sched_barrier(0); \
} while (0)

// ---------------- fused prep: trig table + all f32->bf16 conversions ----------
__device__ __forceinline__ void cvt4(const float* __restrict__ s,
                                     unsigned short* __restrict__ d, int i) {
    float4 v = *reinterpret_cast<const float4*>(s + i);
    *reinterpret_cast<ushort4*>(d + i) =
        make_ushort4(f2bf(v.x), f2bf(v.y), f2bf(v.z), f2bf(v.w));
}

__global__ __launch_bounds__(256) void prep_kernel(
    const float* __restrict__ x, const float* __restrict__ Wq,
    const float* __restrict__ Wkd, const float* __restrict__ Wku,
    const float* __restrict__ wn, const float* __restrict__ Wout,
    unsigned short* __restrict__ xb, unsigned short* __restrict__ wcomb,
    unsigned short* __restrict__ wkub, unsigned short* __restrict__ woutb,
    float* __restrict__ cosT, float* __restrict__ sinT) {
    int bid = blockIdx.x;
    if (bid < 4096) {
        cvt4(x, xb, (bid * 256 + threadIdx.x) * 4);
    } else if (bid < 4352) {
        cvt4(Wq, wcomb, ((bid - 4096) * 256 + threadIdx.x) * 4);
    } else if (bid < 4480) {
        cvt4(Wkd, wcomb + DIMM * DIMM, ((bid - 4352) * 256 + threadIdx.x) * 4);
    } else if (bid < 4736) {
        int i = ((bid - 4480) * 256 + threadIdx.x) * 4;
        float4 v = *reinterpret_cast<const float4*>(Wku + i);
        float4 s = *reinterpret_cast<const float4*>(wn + (i & 255));
        *reinterpret_cast<ushort4*>(wkub + i) =
            make_ushort4(f2bf(v.x * s.x), f2bf(v.y * s.y), f2bf(v.z * s.z), f2bf(v.w * s.w));
    } else if (bid < 4992) {
        cvt4(Wout, woutb, ((bid - 4736) * 256 + threadIdx.x) * 4);
    } else {
        int idx = (bid - 4992) * 256 + threadIdx.x; // < 65536
        int t = idx >> 5, f = idx & 31;
        double freq = pow(10000.0, -(double)f / 32.0);
        double ang = (double)t * freq;
        cosT[idx] = (float)cos(ang);
        sinT[idx] = (float)sin(ang);
    }
}

// ---------------- per-row rsqrt(mean sq) of ckvb0 [B*T, 256] ------------------
__global__ __launch_bounds__(256) void rinv_kernel(const unsigned short* __restrict__ ckvb0,
                                                   float* __restrict__ rinv) {
    int row = blockIdx.x * 4 + (threadIdx.x >> 6);
    int lane = threadIdx.x & 63;
    ushort4 v4 = *reinterpret_cast<const ushort4*>(ckvb0 + (size_t)row * 256 + lane * 4);
    float x0 = bf2f(v4.x), x1 = bf2f(v4.y), x2 = bf2f(v4.z), x3 = bf2f(v4.w);
    float ss = x0 * x0 + x1 * x1 + x2 * x2 + x3 * x3;
#pragma unroll
    for (int off = 32; off > 0; off >>= 1) ss += __shfl_xor(ss, off);
    if (lane == 0) rinv[row] = rsqrtf(ss * (1.0f / RANKK) + 1e-6f);
}

// ---------------- bf16 MFMA GEMM, BK=64, swizzled LDS, 8 waves ----------------
// 128x128 tile, 8 waves (4x2 of 32x64), 2-phase dbuf, global_load_lds staging
// with pre-swizzled source (chunk s holds global chunk s^(row&7)).
// MODE 0: plain f32 C (out = aob @ Wout^T)
// MODE 1: cols<512 -> q-RoPE -> O1 (qb); cols>=512 -> bf16 -> O2 (ckvb0)
// MODE 2: cols<512 -> k-RoPE*rinv -> O1 (kb); cols>=512 -> V^T pack*rinv -> O2 (vT)
template<int MODE>
__global__ __launch_bounds__(512) void gemm_bf(const unsigned short* __restrict__ A,
                                               const unsigned short* __restrict__ W,
                                               float* __restrict__ Cf,
                                               unsigned short* __restrict__ O1,
                                               unsigned short* __restrict__ O2,
                                               const float* __restrict__ cosT,
                                               const float* __restrict__ sinT,
                                               const float* __restrict__ rinvp,
                                               int K, int N) {
    __shared__ __align__(16) unsigned short As[2][128 * 64];   // 32 KB
    __shared__ __align__(16) unsigned short Ws[2][128 * 64];   // 32 KB
    const int tid = threadIdx.x;
    const int lane = tid & 63, w = tid >> 6;       // 8 waves
    const int lr = lane & 15, hi = lane >> 4;
    const int m0 = blockIdx.x * 128, n0 = blockIdx.y * 128;
    const int wr = (w >> 1) * 32, wc = (w & 1) * 64;   // wave tile 32 rows x 64 cols
    // staging: 1024 chunks of 16B per operand; thread handles chunks tid, tid+512
    const int ar1 = tid >> 3;                       // row 0..63
    const int ac1 = ((tid & 7) ^ (ar1 & 7)) << 3;   // pre-swizzled source elem offset
    const int ar2 = ar1 + 64;                       // (ar2&7)==(ar1&7) -> same ac1

    f32x4 acc[2][4];
#pragma unroll
    for (int i = 0; i < 2; ++i)
#pragma unroll
        for (int j = 0; j < 4; ++j) acc[i][j] = 0.0f;

    const int NT = K >> 6;
    auto stage = [&](int t, int b) {
        const int kt = t * 64;
        gload16(A + (size_t)(m0 + ar1) * K + kt + ac1, &As[b][tid * 8]);
        gload16(A + (size_t)(m0 + ar2) * K + kt + ac1, &As[b][(tid + 512) * 8]);
        gload16(W + (size_t)(n0 + ar1) * K + kt + ac1, &Ws[b][tid * 8]);
        gload16(W + (size_t)(n0 + ar2) * K + kt + ac1, &Ws[b][(tid + 512) * 8]);
    };

    stage(0, 0);
    WAIT_VM0_BARRIER();
    for (int t = 0; t < NT; ++t) {
        const int cur = t & 1;
        if (t + 1 < NT) stage(t + 1, cur ^ 1);
        bf8_t af[2][2], bw[4][2];
#pragma unroll
        for (int i = 0; i < 2; ++i) {
            int row = wr + i * 16 + lr;
#pragma unroll
            for (int kk = 0; kk < 2; ++kk)
                af[i][kk] = *reinterpret_cast<const bf8_t*>(
                    &As[cur][row * 64 + (((kk * 4 + hi) ^ (row & 7)) << 3)]);
        }
#pragma unroll
        for (int j = 0; j < 4; ++j) {
            int row = wc + j * 16 + lr;
#pragma unroll
            for (int kk = 0; kk < 2; ++kk)
                bw[j][kk] = *reinterpret_cast<const bf8_t*>(
                    &Ws[cur][row * 64 + (((kk * 4 + hi) ^ (row & 7)) << 3)]);
        }
#pragma unroll
        for (int kk = 0; kk < 2; ++kk)
#pragma unroll
            for (int i = 0; i < 2; ++i)
#pragma unroll
                for (int j = 0; j < 4; ++j)
                    acc[i][j] = __builtin_amdgcn_mfma_f32_16x16x32_bf16(af[i][kk], bw[j][kk], acc[i][j], 0, 0, 0);
        if (t + 1 < NT) WAIT_VM0_BARRIER();
    }

    if constexpr (MODE == 0) {
#pragma unroll
        for (int i = 0; i < 2; ++i)
#pragma unroll
            for (int j = 0; j < 4; ++j)
#pragma unroll
                for (int r = 0; r < 4; ++r)
                    Cf[(size_t)(m0 + wr + i * 16 + 4 * hi + r) * N + n0 + wc + j * 16 + lr] = acc[i][j][r];
    } else if (n0 < 512) {
        // RoPE epilogue -> O1 in [B*H, T, HD] bf16 (MODE 2 additionally scales by rinv)
        int h = (n0 + wc) >> 6;
#pragma unroll
        for (int i = 0; i < 2; ++i) {
            int tb = m0 + wr + i * 16 + 4 * hi;
            float4 rv4 = make_float4(1.f, 1.f, 1.f, 1.f);
            if constexpr (MODE == 2) rv4 = *reinterpret_cast<const float4*>(rinvp + tb);
#pragma unroll
            for (int j = 0; j < 2; ++j)
#pragma unroll
                for (int r = 0; r < 4; ++r) {
                    int t = tb + r;
                    int b = t >> 11, tt = t & 2047;
                    int ff = j * 16 + lr;
                    float rv = (&rv4.x)[r];
                    float x1 = acc[i][j][r] * rv, x2 = acc[i][j + 2][r] * rv;
                    float cc = cosT[tt * 32 + ff], ss = sinT[tt * 32 + ff];
                    unsigned short* dp = O1 + ((size_t)((b * 8 + h) * 2048 + tt)) * 64;
                    dp[ff]      = f2bf(x1 * cc - x2 * ss);
                    dp[ff + 32] = f2bf(x2 * cc + x1 * ss);
                }
        }
    } else if constexpr (MODE == 1) {
        // ckv region: bf16 compact [B*T, 256] (unnormalized; rinv applied downstream)
        int cb = n0 - 512 + wc;
#pragma unroll
        for (int i = 0; i < 2; ++i)
#pragma unroll
            for (int j = 0; j < 4; ++j)
#pragma unroll
                for (int r = 0; r < 4; ++r)
                    O2[(size_t)(m0 + wr + i * 16 + 4 * hi + r) * 256 + cb + j * 16 + lr] = f2bf(acc[i][j][r]);
    } else {
        // MODE 2, V region: transposed pack * rinv -> vT [B*H, HD, T] bf16
        int cb = n0 + wc - 512;
        int h = cb >> 6;
#pragma unroll
        for (int i = 0; i < 2; ++i) {
            int tb = m0 + wr + i * 16 + 4 * hi;
            int b = tb >> 11, tt = tb & 2047;
            float4 rv4 = *reinterpret_cast<const float4*>(rinvp + tb);
#pragma unroll
            for (int j = 0; j < 4; ++j) {
                int hd = j * 16 + lr;
                ushort4 o = make_ushort4(f2bf(acc[i][j][0] * rv4.x), f2bf(acc[i][j][1] * rv4.y),
                                         f2bf(acc[i][j][2] * rv4.z), f2bf(acc[i][j][3] * rv4.w));
                *reinterpret_cast<ushort4*>(O2 + (((size_t)(b * 8 + h) * 64 + hd) * 2048 + tt)) = o;
            }
        }
    }
}

// ---------------- MFMA flash attention, QBLK=128, 2-phase dbuf pipeline -------
// 512 blocks (XCD-swizzled), 512 thr = 8 waves. 64-key tiles, fixed-max softmax.
__global__ __launch_bounds__(512) void attn_mfma(const unsigned short* __restrict__ qbf,
                                                 const unsigned short* __restrict__ kbf,
                                                 const unsigned short* __restrict__ vT,
                                                 unsigned short* __restrict__ aob) {
    __shared__ __align__(16) unsigned short Kl[2][64 * 64];
    __shared__ __align__(16) unsigned short Vl[2][64 * 64];
    __shared__ unsigned short Pl[128][72];
    const int tid = threadIdx.x;
    const int lane = tid & 63, w = tid >> 6;        // 8 waves
    const int lr = lane & 15, hi = lane >> 4;

    // bijective XCD swizzle: 512 = 8 XCDs x 64; each XCD owns 4 bh values
    const int fid = blockIdx.x;
    const int swz = (fid & 7) * 64 + (fid >> 3);
    const int t0 = (swz & 15) * 128;
    const int bh = swz >> 4;

    const unsigned short* qp = qbf + ((size_t)bh * TT + t0 + w * 16 + lr) * HDIM;
    bf8_t qa[2];
    qa[0] = *reinterpret_cast<const bf8_t*>(qp + hi * 8);
    qa[1] = *reinterpret_cast<const bf8_t*>(qp + 32 + hi * 8);

    f32x4 oc[4];
#pragma unroll
    for (int f = 0; f < 4; ++f) oc[f] = 0.0f;
    float lp[4] = {0.f, 0.f, 0.f, 0.f};

    const int smin = max(0, t0 - WINN);
    const int smax = min(TT, t0 + 128 + WINN);
    const int NT = (smax - smin) >> 6;

    const int st_row = tid >> 3;            // 0..63
    const int st_c = tid & 7;               // 16B chunk
    const int st_cs = (st_c ^ (st_row & 7)) << 3;   // pre-swizzled source elem offset

    auto stage = [&](int t, int b) {
        const int s0 = smin + t * 64;
        gload16(kbf + ((size_t)bh * TT + s0 + st_row) * HDIM + st_cs, &Kl[b][tid * 8]);
        gload16(vT + ((size_t)bh * 64 + st_row) * TT + s0 + st_cs, &Vl[b][tid * 8]);
    };

    stage(0, 0);
    WAIT_VM0_BARRIER();
    for (int t = 0; t < NT; ++t) {
        const int cur = t & 1;
        if (t + 1 < NT) stage(t + 1, cur ^ 1);
        const int s0 = smin + t * 64;

        // QK^T: S[16q][64key] per wave
        f32x4 sacc[4];
#pragma unroll
        for (int f = 0; f < 4; ++f) sacc[f] = 0.0f;
        __builtin_amdgcn_s_setprio(1);
#pragma unroll
        for (int ks = 0; ks < 2; ++ks)
#pragma unroll
            for (int f = 0; f < 4; ++f) {
                int row = f * 16 + lr;
                bf8_t kb = *reinterpret_cast<const bf8_t*>(
                    &Kl[cur][row * 64 + (((ks * 4 + hi) ^ (row & 7)) << 3)]);
                sacc[f] = __builtin_amdgcn_mfma_f32_16x16x32_bf16(qa[ks], kb, sacc[f], 0, 0, 0);
            }
        __builtin_amdgcn_s_setprio(0);

        const int off_w = s0 - t0 - w * 16;
        const bool edge = (off_w + 63 > WINN) || (off_w - 15 < -WINN);
#pragma unroll
        for (int f = 0; f < 4; ++f)
#pragma unroll
            for (int r = 0; r < 4; ++r) {
                float p;
                if (edge) {
                    int d = off_w + f * 16 + lr - 4 * hi - r;
                    p = (d <= WINN && d >= -WINN) ? exp2f(sacc[f][r] * SC2) : 0.f;
                } else {
                    p = exp2f(sacc[f][r] * SC2);
                }
                lp[r] += p;
                Pl[w * 16 + 4 * hi + r][f * 16 + lr] = f2bf(p);
            }

        // PV: out[16q][64hd] += P[16q][64key] * V^T
        __builtin_amdgcn_s_setprio(1);
#pragma unroll
        for (int ks = 0; ks < 2; ++ks) {
            bf8_t pa = *reinterpret_cast<const bf8_t*>(&Pl[w * 16 + lr][ks * 32 + hi * 8]);
#pragma unroll
            for (int f = 0; f < 4; ++f) {
                int row = f * 16 + lr;
                bf8_t vb = *reinterpret_cast<const bf8_t*>(
                    &Vl[cur][row * 64 + (((ks * 4 + hi) ^ (row & 7)) << 3)]);
                oc[f] = __builtin_amdgcn_mfma_f32_16x16x32_bf16(pa, vb, oc[f], 0, 0, 0);
            }
        }
        __builtin_amdgcn_s_setprio(0);
        if (t + 1 < NT) WAIT_VM0_BARRIER();
    }

    // deferred l reduction over the 16 lr lanes
#pragma unroll
    for (int r = 0; r < 4; ++r) {
        lp[r] += __shfl_xor(lp[r], 1);
        lp[r] += __shfl_xor(lp[r], 2);
        lp[r] += __shfl_xor(lp[r], 4);
        lp[r] += __shfl_xor(lp[r], 8);
    }

    int b = bh >> 3, h = bh & 7;
#pragma unroll
    for (int r = 0; r < 4; ++r) {
        float inv = 1.0f / lp[r];
        int t = t0 + w * 16 + 4 * hi + r;
        unsigned short* op = aob + ((size_t)b * TT + t) * DIMM + h * HDIM;
#pragma unroll
        for (int f = 0; f < 4; ++f)
            op[f * 16 + lr] = f2bf(oc[f][r] * inv);
    }
}

// ---------------- launch ------------------------------------------------------
extern "C" void kernel_launch(void* const* d_in, const int* in_sizes, int n_in,
                              void* d_out, int out_size, void* d_ws, size_t ws_size,
                              hipStream_t stream) {
    const float* x     = (const float*)d_in[0];
    const float* Wq    = (const float*)d_in[1];
    const float* Wkd   = (const float*)d_in[2];
    const float* wnorm = (const float*)d_in[3];
    const float* Wku   = (const float*)d_in[4];
    const float* Wout  = (const float*)d_in[5];
    float* out = (float*)d_out;
    char* ws = (char*)d_ws;

    unsigned short* xb    = (unsigned short*)(ws + 0);          //  8,388,608
    unsigned short* qb    = (unsigned short*)(ws + 8388608);    //  8,388,608
    unsigned short* kb    = (unsigned short*)(ws + 16777216);   //  8,388,608
    unsigned short* vTb   = (unsigned short*)(ws + 25165824);   //  8,388,608
    unsigned short* ckvb0 = (unsigned short*)(ws + 33554432);   //  4,194,304
    unsigned short* aob   = (unsigned short*)(ws + 37748736);   //  8,388,608
    unsigned short* wcomb = (unsigned short*)(ws + 46137344);   //    786,432
    unsigned short* wkub  = (unsigned short*)(ws + 46923776);   //    524,288
    unsigned short* woutb = (unsigned short*)(ws + 47448064);   //    524,288
    float*          rinvb = (float*)(ws + 47972352);            //     32,768
    float*          cosT  = (float*)(ws + 48005120);            //    262,144
    float*          sinT  = (float*)(ws + 48267264);            //    262,144

    prep_kernel<<<5248, 256, 0, stream>>>(x, Wq, Wkd, Wku, wnorm, Wout,
                                          xb, wcomb, wkub, woutb, cosT, sinT);

    // fused q + kv_down projection (+ q-RoPE, ckv write): [8192, 768]
    gemm_bf<1><<<dim3(BT / 128, 6), 512, 0, stream>>>(xb, wcomb, nullptr, qb, ckvb0,
                                                      cosT, sinT, nullptr, DIMM, 768);
    rinv_kernel<<<BT / 4, 256, 0, stream>>>(ckvb0, rinvb);

    // kv up-projection (+ k-RoPE*rinv, V^T pack*rinv): [8192, 1024]
    gemm_bf<2><<<dim3(BT / 128, 8), 512, 0, stream>>>(ckvb0, wkub, nullptr, kb, vTb,
                                                      cosT, sinT, rinvb, RANKK, 1024);

    // attention
    attn_mfma<<<512, 512, 0, stream>>>(qb, kb, vTb, aob);

    // out = aob @ Wout^T (f32)
    gemm_bf<0><<<dim3(BT / 128, 4), 512, 0, stream>>>(aob, woutb, out, nullptr, nullptr,
                                                      nullptr, nullptr, nullptr, DIMM, DIMM);
}

// Round 7
// 73.754 us; speedup vs baseline: 130.3906x; 1.0565x over previous
//
#include <hip/hip_runtime.h>
#include <math.h>

#define BB 4
#define TT 2048
#define DIMM 512
#define HEADS 8
#define HDIM 64
#define RANKK 256
#define WINN 256

static constexpr int BT = BB * TT; // 8192
#define SC2 0.1803368801111244f   // 0.125 * log2(e)

typedef short bf8_t __attribute__((ext_vector_type(8)));   // 8 bf16 payload
typedef float f32x4 __attribute__((ext_vector_type(4)));

__device__ __forceinline__ unsigned short f2bf(float f) {
    unsigned u = __float_as_uint(f);
    u += 0x7fffu + ((u >> 16) & 1u);     // round-to-nearest-even
    return (unsigned short)(u >> 16);
}
__device__ __forceinline__ unsigned f2bf2(float a, float b) {  // lo=a, hi=b, RNE
    unsigned r;
    asm("v_cvt_pk_bf16_f32 %0, %1, %2" : "=v"(r) : "v"(a), "v"(b));
    return r;
}

typedef __attribute__((address_space(1))) void gvoid_t;
typedef __attribute__((address_space(3))) void lvoid_t;
__device__ __forceinline__ void gload16(const void* g, void* l) {
    __builtin_amdgcn_global_load_lds((gvoid_t*)g, (lvoid_t*)l, 16, 0, 0);
}
#define WAIT_VM0_BARRIER() do { \
    asm volatile("s_waitcnt vmcnt(0)" ::: "memory"); \
    __builtin_amdgcn_s_barrier(); \
    __builtin_amdgcn_sched_barrier(0); \
} while (0)

// ---------------- fused prep: trig table + all f32->bf16 conversions ----------
__device__ __forceinline__ void cvt4(const float* __restrict__ s,
                                     unsigned short* __restrict__ d, int i) {
    float4 v = *reinterpret_cast<const float4*>(s + i);
    uint2 st = make_uint2(f2bf2(v.x, v.y), f2bf2(v.z, v.w));
    *reinterpret_cast<uint2*>(d + i) = st;
}

__global__ __launch_bounds__(256) void prep_kernel(
    const float* __restrict__ x, const float* __restrict__ Wq,
    const float* __restrict__ Wkd, const float* __restrict__ Wku,
    const float* __restrict__ wn, const float* __restrict__ Wout,
    unsigned short* __restrict__ xb, unsigned short* __restrict__ wcomb,
    unsigned short* __restrict__ wkub, unsigned short* __restrict__ woutb,
    float* __restrict__ cosT, float* __restrict__ sinT) {
    int bid = blockIdx.x;
    if (bid < 4096) {
        cvt4(x, xb, (bid * 256 + threadIdx.x) * 4);
    } else if (bid < 4352) {
        cvt4(Wq, wcomb, ((bid - 4096) * 256 + threadIdx.x) * 4);
    } else if (bid < 4480) {
        cvt4(Wkd, wcomb + DIMM * DIMM, ((bid - 4352) * 256 + threadIdx.x) * 4);
    } else if (bid < 4736) {
        int i = ((bid - 4480) * 256 + threadIdx.x) * 4;
        float4 v = *reinterpret_cast<const float4*>(Wku + i);
        float4 s = *reinterpret_cast<const float4*>(wn + (i & 255));
        uint2 st = make_uint2(f2bf2(v.x * s.x, v.y * s.y), f2bf2(v.z * s.z, v.w * s.w));
        *reinterpret_cast<uint2*>(wkub + i) = st;
    } else if (bid < 4992) {
        cvt4(Wout, woutb, ((bid - 4736) * 256 + threadIdx.x) * 4);
    } else {
        int idx = (bid - 4992) * 256 + threadIdx.x; // < 65536
        int t = idx >> 5, f = idx & 31;
        double freq = pow(10000.0, -(double)f / 32.0);
        double ang = (double)t * freq;
        cosT[idx] = (float)cos(ang);
        sinT[idx] = (float)sin(ang);
    }
}

// ---------------- bf16 MFMA GEMM, BK=64, swizzled LDS, fused epilogues --------
// BMx128 tile, BM/16 waves of 32x64, 2-phase dbuf, global_load_lds staging
// with pre-swizzled source (dest chunk c holds global chunk c^(row&7)).
// MODE 0: plain f32 C (out = aob @ Wout^T)                         [BM=64]
// MODE 1: cols<512 -> q-RoPE -> O1 (qb); cols>=512 -> bf16 -> O2 (ckvb0)
//         + per-row sumsq partials -> ssum[4][8192]                [BM=128]
// MODE 2: cols<512 -> k-RoPE*rinv -> O1 (kb); cols>=512 -> V^T*rinv -> O2 (vT);
//         rinv computed from ssum                                  [BM=128]
template<int MODE, int BM>
__global__ __launch_bounds__(BM * 4) void gemm_bf(const unsigned short* __restrict__ A,
                                                  const unsigned short* __restrict__ W,
                                                  float* __restrict__ Cf,
                                                  unsigned short* __restrict__ O1,
                                                  unsigned short* __restrict__ O2,
                                                  const float* __restrict__ cosT,
                                                  const float* __restrict__ sinT,
                                                  float* __restrict__ ssum,
                                                  int K, int N) {
    __shared__ __align__(16) unsigned short As[2][BM * 64];
    __shared__ __align__(16) unsigned short Ws[2][128 * 64];
    const int tid = threadIdx.x;
    const int lane = tid & 63, w = tid >> 6;       // BM/16 waves
    const int lr = lane & 15, hi = lane >> 4;
    const int m0 = blockIdx.x * BM, n0 = blockIdx.y * 128;
    const int wr = (w >> 1) * 32, wc = (w & 1) * 64;   // wave tile 32 rows x 64 cols

    f32x4 acc[2][4];
#pragma unroll
    for (int i = 0; i < 2; ++i)
#pragma unroll
        for (int j = 0; j < 4; ++j) acc[i][j] = 0.0f;

    const int NT = K >> 6;
    auto stage = [&](int t, int b) {
        const int kt = t * 64;
#pragma unroll
        for (int c = tid; c < BM * 8; c += BM * 4) {
            int row = c >> 3, sc = ((c & 7) ^ (row & 7)) << 3;
            gload16(A + (size_t)(m0 + row) * K + kt + sc, &As[b][c * 8]);
        }
#pragma unroll
        for (int c = tid; c < 1024; c += BM * 4) {
            int row = c >> 3, sc = ((c & 7) ^ (row & 7)) << 3;
            gload16(W + (size_t)(n0 + row) * K + kt + sc, &Ws[b][c * 8]);
        }
    };

    stage(0, 0);
    WAIT_VM0_BARRIER();
    for (int t = 0; t < NT; ++t) {
        const int cur = t & 1;
        if (t + 1 < NT) stage(t + 1, cur ^ 1);
        bf8_t af[2][2], bw[4][2];
#pragma unroll
        for (int i = 0; i < 2; ++i) {
            int row = wr + i * 16 + lr;
#pragma unroll
            for (int kk = 0; kk < 2; ++kk)
                af[i][kk] = *reinterpret_cast<const bf8_t*>(
                    &As[cur][row * 64 + (((kk * 4 + hi) ^ (row & 7)) << 3)]);
        }
#pragma unroll
        for (int j = 0; j < 4; ++j) {
            int row = wc + j * 16 + lr;
#pragma unroll
            for (int kk = 0; kk < 2; ++kk)
                bw[j][kk] = *reinterpret_cast<const bf8_t*>(
                    &Ws[cur][row * 64 + (((kk * 4 + hi) ^ (row & 7)) << 3)]);
        }
#pragma unroll
        for (int kk = 0; kk < 2; ++kk)
#pragma unroll
            for (int i = 0; i < 2; ++i)
#pragma unroll
                for (int j = 0; j < 4; ++j)
                    acc[i][j] = __builtin_amdgcn_mfma_f32_16x16x32_bf16(af[i][kk], bw[j][kk], acc[i][j], 0, 0, 0);
        if (t + 1 < NT) WAIT_VM0_BARRIER();
    }

    if constexpr (MODE == 0) {
#pragma unroll
        for (int i = 0; i < 2; ++i)
#pragma unroll
            for (int j = 0; j < 4; ++j)
#pragma unroll
                for (int r = 0; r < 4; ++r)
                    Cf[(size_t)(m0 + wr + i * 16 + 4 * hi + r) * N + n0 + wc + j * 16 + lr] = acc[i][j][r];
    } else if (n0 < 512) {
        // RoPE epilogue -> O1 in [B*H, T, HD] bf16 (MODE 2 additionally scales by rinv)
        int h = (n0 + wc) >> 6;
#pragma unroll
        for (int i = 0; i < 2; ++i) {
            int tb = m0 + wr + i * 16 + 4 * hi;
            float4 rv4 = make_float4(1.f, 1.f, 1.f, 1.f);
            if constexpr (MODE == 2) {
                float4 sa = *reinterpret_cast<const float4*>(ssum + tb);
                float4 sb = *reinterpret_cast<const float4*>(ssum + 8192 + tb);
                float4 sc = *reinterpret_cast<const float4*>(ssum + 16384 + tb);
                float4 sd = *reinterpret_cast<const float4*>(ssum + 24576 + tb);
                rv4.x = rsqrtf((sa.x + sb.x + sc.x + sd.x) * (1.0f / RANKK) + 1e-6f);
                rv4.y = rsqrtf((sa.y + sb.y + sc.y + sd.y) * (1.0f / RANKK) + 1e-6f);
                rv4.z = rsqrtf((sa.z + sb.z + sc.z + sd.z) * (1.0f / RANKK) + 1e-6f);
                rv4.w = rsqrtf((sa.w + sb.w + sc.w + sd.w) * (1.0f / RANKK) + 1e-6f);
            }
#pragma unroll
            for (int j = 0; j < 2; ++j)
#pragma unroll
                for (int r = 0; r < 4; ++r) {
                    int t = tb + r;
                    int b = t >> 11, tt = t & 2047;
                    int ff = j * 16 + lr;
                    float rv = (&rv4.x)[r];
                    float x1 = acc[i][j][r] * rv, x2 = acc[i][j + 2][r] * rv;
                    float cc = cosT[tt * 32 + ff], ss = sinT[tt * 32 + ff];
                    unsigned u = f2bf2(x1 * cc - x2 * ss, x2 * cc + x1 * ss);
                    unsigned short* dp = O1 + ((size_t)((b * 8 + h) * 2048 + tt)) * 64;
                    dp[ff]      = (unsigned short)u;
                    dp[ff + 32] = (unsigned short)(u >> 16);
                }
        }
    } else if constexpr (MODE == 1) {
        // ckv region: bf16 compact [B*T, 256] + deterministic per-row sumsq partials
        int cb = n0 - 512 + wc;
        int part = ((n0 - 512) >> 7) * 2 + (w & 1);
#pragma unroll
        for (int i = 0; i < 2; ++i) {
            int tb = m0 + wr + i * 16 + 4 * hi;
#pragma unroll
            for (int r = 0; r < 4; ++r) {
                float ps = acc[i][0][r] * acc[i][0][r] + acc[i][1][r] * acc[i][1][r]
                         + acc[i][2][r] * acc[i][2][r] + acc[i][3][r] * acc[i][3][r];
                ps += __shfl_xor(ps, 1);
                ps += __shfl_xor(ps, 2);
                ps += __shfl_xor(ps, 4);
                ps += __shfl_xor(ps, 8);
                if (lr == 0) ssum[part * 8192 + tb + r] = ps;
            }
#pragma unroll
            for (int j = 0; j < 4; ++j) {
                unsigned a01 = f2bf2(acc[i][j][0], acc[i][j][1]);
                unsigned a23 = f2bf2(acc[i][j][2], acc[i][j][3]);
                unsigned short* dp = O2 + (size_t)tb * 256 + cb + j * 16 + lr;
                dp[0]   = (unsigned short)a01;
                dp[256] = (unsigned short)(a01 >> 16);
                dp[512] = (unsigned short)a23;
                dp[768] = (unsigned short)(a23 >> 16);
            }
        }
    } else {
        // MODE 2, V region: transposed pack * rinv -> vT [B*H, HD, T] bf16
        int cb = n0 + wc - 512;
        int h = cb >> 6;
#pragma unroll
        for (int i = 0; i < 2; ++i) {
            int tb = m0 + wr + i * 16 + 4 * hi;
            int b = tb >> 11, tt = tb & 2047;
            float4 sa = *reinterpret_cast<const float4*>(ssum + tb);
            float4 sb = *reinterpret_cast<const float4*>(ssum + 8192 + tb);
            float4 sc = *reinterpret_cast<const float4*>(ssum + 16384 + tb);
            float4 sd = *reinterpret_cast<const float4*>(ssum + 24576 + tb);
            float4 rv4;
            rv4.x = rsqrtf((sa.x + sb.x + sc.x + sd.x) * (1.0f / RANKK) + 1e-6f);
            rv4.y = rsqrtf((sa.y + sb.y + sc.y + sd.y) * (1.0f / RANKK) + 1e-6f);
            rv4.z = rsqrtf((sa.z + sb.z + sc.z + sd.z) * (1.0f / RANKK) + 1e-6f);
            rv4.w = rsqrtf((sa.w + sb.w + sc.w + sd.w) * (1.0f / RANKK) + 1e-6f);
#pragma unroll
            for (int j = 0; j < 4; ++j) {
                int hd = j * 16 + lr;
                uint2 st = make_uint2(f2bf2(acc[i][j][0] * rv4.x, acc[i][j][1] * rv4.y),
                                      f2bf2(acc[i][j][2] * rv4.z, acc[i][j][3] * rv4.w));
                *reinterpret_cast<uint2*>(O2 + (((size_t)(b * 8 + h) * 64 + hd) * 2048 + tt)) = st;
            }
        }
    }
}

// ---------------- MFMA flash attention, QBLK=128, 2-phase dbuf pipeline -------
// 512 blocks (XCD-swizzled), 512 thr = 8 waves. 64-key tiles, fixed-max softmax.
__global__ __launch_bounds__(512) void attn_mfma(const unsigned short* __restrict__ qbf,
                                                 const unsigned short* __restrict__ kbf,
                                                 const unsigned short* __restrict__ vT,
                                                 unsigned short* __restrict__ aob) {
    __shared__ __align__(16) unsigned short Kl[2][64 * 64];
    __shared__ __align__(16) unsigned short Vl[2][64 * 64];
    __shared__ unsigned short Pl[128][72];
    const int tid = threadIdx.x;
    const int lane = tid & 63, w = tid >> 6;        // 8 waves
    const int lr = lane & 15, hi = lane >> 4;

    // bijective XCD swizzle: 512 = 8 XCDs x 64; each XCD owns 4 bh values
    const int fid = blockIdx.x;
    const int swz = (fid & 7) * 64 + (fid >> 3);
    const int t0 = (swz & 15) * 128;
    const int bh = swz >> 4;

    const unsigned short* qp = qbf + ((size_t)bh * TT + t0 + w * 16 + lr) * HDIM;
    bf8_t qa[2];
    qa[0] = *reinterpret_cast<const bf8_t*>(qp + hi * 8);
    qa[1] = *reinterpret_cast<const bf8_t*>(qp + 32 + hi * 8);

    f32x4 oc[4];
#pragma unroll
    for (int f = 0; f < 4; ++f) oc[f] = 0.0f;
    float lp[4] = {0.f, 0.f, 0.f, 0.f};

    const int smin = max(0, t0 - WINN);
    const int smax = min(TT, t0 + 128 + WINN);
    const int NT = (smax - smin) >> 6;

    const int st_row = tid >> 3;            // 0..63
    const int st_c = tid & 7;               // 16B chunk
    const int st_cs = (st_c ^ (st_row & 7)) << 3;   // pre-swizzled source elem offset

    auto stage = [&](int t, int b) {
        const int s0 = smin + t * 64;
        gload16(kbf + ((size_t)bh * TT + s0 + st_row) * HDIM + st_cs, &Kl[b][tid * 8]);
        gload16(vT + ((size_t)bh * 64 + st_row) * TT + s0 + st_cs, &Vl[b][tid * 8]);
    };

    stage(0, 0);
    WAIT_VM0_BARRIER();
    for (int t = 0; t < NT; ++t) {
        const int cur = t & 1;
        if (t + 1 < NT) stage(t + 1, cur ^ 1);
        const int s0 = smin + t * 64;

        // QK^T: S[16q][64key] per wave
        f32x4 sacc[4];
#pragma unroll
        for (int f = 0; f < 4; ++f) sacc[f] = 0.0f;
        __builtin_amdgcn_s_setprio(1);
#pragma unroll
        for (int ks = 0; ks < 2; ++ks)
#pragma unroll
            for (int f = 0; f < 4; ++f) {
                int row = f * 16 + lr;
                bf8_t kb = *reinterpret_cast<const bf8_t*>(
                    &Kl[cur][row * 64 + (((ks * 4 + hi) ^ (row & 7)) << 3)]);
                sacc[f] = __builtin_amdgcn_mfma_f32_16x16x32_bf16(qa[ks], kb, sacc[f], 0, 0, 0);
            }
        __builtin_amdgcn_s_setprio(0);

        const int off_w = s0 - t0 - w * 16;
        const bool edge = (off_w + 63 > WINN) || (off_w - 15 < -WINN);
#pragma unroll
        for (int f = 0; f < 4; ++f) {
            float p[4];
#pragma unroll
            for (int r = 0; r < 4; ++r) {
                float v;
                if (edge) {
                    int d = off_w + f * 16 + lr - 4 * hi - r;
                    v = (d <= WINN && d >= -WINN) ? exp2f(sacc[f][r] * SC2) : 0.f;
                } else {
                    v = exp2f(sacc[f][r] * SC2);
                }
                p[r] = v;
                lp[r] += v;
            }
            unsigned a01 = f2bf2(p[0], p[1]);
            unsigned a23 = f2bf2(p[2], p[3]);
            unsigned short* bp = &Pl[w * 16 + 4 * hi][f * 16 + lr];
            bp[0]   = (unsigned short)a01;
            bp[72]  = (unsigned short)(a01 >> 16);
            bp[144] = (unsigned short)a23;
            bp[216] = (unsigned short)(a23 >> 16);
        }

        // PV: out[16q][64hd] += P[16q][64key] * V^T
        __builtin_amdgcn_s_setprio(1);
#pragma unroll
        for (int ks = 0; ks < 2; ++ks) {
            bf8_t pa = *reinterpret_cast<const bf8_t*>(&Pl[w * 16 + lr][ks * 32 + hi * 8]);
#pragma unroll
            for (int f = 0; f < 4; ++f) {
                int row = f * 16 + lr;
                bf8_t vb = *reinterpret_cast<const bf8_t*>(
                    &Vl[cur][row * 64 + (((ks * 4 + hi) ^ (row & 7)) << 3)]);
                oc[f] = __builtin_amdgcn_mfma_f32_16x16x32_bf16(pa, vb, oc[f], 0, 0, 0);
            }
        }
        __builtin_amdgcn_s_setprio(0);
        if (t + 1 < NT) WAIT_VM0_BARRIER();
    }

    // deferred l reduction over the 16 lr lanes
#pragma unroll
    for (int r = 0; r < 4; ++r) {
        lp[r] += __shfl_xor(lp[r], 1);
        lp[r] += __shfl_xor(lp[r], 2);
        lp[r] += __shfl_xor(lp[r], 4);
        lp[r] += __shfl_xor(lp[r], 8);
    }

    int b = bh >> 3, h = bh & 7;
#pragma unroll
    for (int r = 0; r < 4; ++r) {
        float inv = 1.0f / lp[r];
        int t = t0 + w * 16 + 4 * hi + r;
        unsigned short* op = aob + ((size_t)b * TT + t) * DIMM + h * HDIM;
        unsigned u0 = f2bf2(oc[0][r] * inv, oc[1][r] * inv);
        unsigned u1 = f2bf2(oc[2][r] * inv, oc[3][r] * inv);
        op[lr]      = (unsigned short)u0;
        op[16 + lr] = (unsigned short)(u0 >> 16);
        op[32 + lr] = (unsigned short)u1;
        op[48 + lr] = (unsigned short)(u1 >> 16);
    }
}

// ---------------- launch ------------------------------------------------------
extern "C" void kernel_launch(void* const* d_in, const int* in_sizes, int n_in,
                              void* d_out, int out_size, void* d_ws, size_t ws_size,
                              hipStream_t stream) {
    const float* x     = (const float*)d_in[0];
    const float* Wq    = (const float*)d_in[1];
    const float* Wkd   = (const float*)d_in[2];
    const float* wnorm = (const float*)d_in[3];
    const float* Wku   = (const float*)d_in[4];
    const float* Wout  = (const float*)d_in[5];
    float* out = (float*)d_out;
    char* ws = (char*)d_ws;

    unsigned short* xb    = (unsigned short*)(ws + 0);          //  8,388,608
    unsigned short* qb    = (unsigned short*)(ws + 8388608);    //  8,388,608
    unsigned short* kb    = (unsigned short*)(ws + 16777216);   //  8,388,608
    unsigned short* vTb   = (unsigned short*)(ws + 25165824);   //  8,388,608
    unsigned short* ckvb0 = (unsigned short*)(ws + 33554432);   //  4,194,304
    unsigned short* aob   = (unsigned short*)(ws + 37748736);   //  8,388,608
    unsigned short* wcomb = (unsigned short*)(ws + 46137344);   //    786,432
    unsigned short* wkub  = (unsigned short*)(ws + 46923776);   //    524,288
    unsigned short* woutb = (unsigned short*)(ws + 47448064);   //    524,288
    float*          cosT  = (float*)(ws + 48005120);            //    262,144
    float*          sinT  = (float*)(ws + 48267264);            //    262,144
    float*          ssum  = (float*)(ws + 48529408);            //    131,072 [4][8192]

    prep_kernel<<<5248, 256, 0, stream>>>(x, Wq, Wkd, Wku, wnorm, Wout,
                                          xb, wcomb, wkub, woutb, cosT, sinT);

    // fused q + kv_down projection (+ q-RoPE, ckv write, sumsq partials): [8192, 768]
    gemm_bf<1, 128><<<dim3(BT / 128, 6), 512, 0, stream>>>(xb, wcomb, nullptr, qb, ckvb0,
                                                           cosT, sinT, ssum, DIMM, 768);

    // kv up-projection (+ k-RoPE*rinv, V^T pack*rinv; rinv from ssum): [8192, 1024]
    gemm_bf<2, 128><<<dim3(BT / 128, 8), 512, 0, stream>>>(ckvb0, wkub, nullptr, kb, vTb,
                                                           cosT, sinT, ssum, RANKK, 1024);

    // attention
    attn_mfma<<<512, 512, 0, stream>>>(qb, kb, vTb, aob);

    // out = aob @ Wout^T (f32), BM=64 for occupancy (512 blocks, 3/CU)
    gemm_bf<0, 64><<<dim3(BT / 64, 4), 256, 0, stream>>>(aob, woutb, out, nullptr, nullptr,
                                                         nullptr, nullptr, nullptr, DIMM, DIMM);
}